// Round 4
// baseline (510.601 us; speedup 1.0000x reference)
//
#include <hip/hip_runtime.h>
#include <hip/hip_bf16.h>

#define HID 128
#define LMD 1024
#define BGR 64
#define NPG 501
#define NN (BGR*NPG)
#define NRELT 42
#define NEG 0.2f
#define TPART ((size_t)BGR*HID*HID)

typedef short bf16x8 __attribute__((ext_vector_type(8)));
typedef short bf16x4 __attribute__((ext_vector_type(4)));
typedef float f32x4  __attribute__((ext_vector_type(4)));

__device__ __forceinline__ short f2bf(float x){
  union { float f; unsigned u; } v; v.f = x;
  unsigned r = v.u + 0x7FFFu + ((v.u >> 16) & 1u);
  return (short)(r >> 16);
}
__device__ __forceinline__ float bf2f(short h){
  union { unsigned u; float f; } v; v.u = ((unsigned)(unsigned short)h) << 16;
  return v.f;
}
// split x ~= hi + lo (both bf16)
__device__ __forceinline__ void fsplit(float x, short& hi, short& lo){
  hi = f2bf(x);
  lo = f2bf(x - bf2f(hi));
}

// merged setup: te / W_gat^T->bf16 hi+lo / lm->bf16 hi+lo / zero / ctx_emb
__global__ void k_setup(const float* __restrict__ W_edge, const float* __restrict__ att_edge,
                        const float* __restrict__ etab, float* __restrict__ te,
                        const float* __restrict__ W_gat, short* __restrict__ wtg_hi,
                        short* __restrict__ wtg_lo,
                        const float* __restrict__ lm, short* __restrict__ lmb_hi,
                        short* __restrict__ lmb_lo,
                        const float* __restrict__ W_lm, const float* __restrict__ b_lm,
                        float* __restrict__ ctx_emb,
                        int* __restrict__ deg, float* __restrict__ asum,
                        int* __restrict__ counter){
  const int bid = blockIdx.x, t = threadIdx.x;
  if (bid == 0){
    __shared__ float we[HID];
    if (t < HID){
      float s = 0.f;
      for (int j=0;j<HID;++j) s += W_edge[t*HID+j]*att_edge[j];
      we[t] = s;
    }
    __syncthreads();
    if (t < NRELT){
      float s = 0.f;
      for (int i=0;i<HID;++i) s += etab[t*HID+i]*we[i];
      te[t] = s;
    }
  } else if (bid <= 128){
    int k = bid - 1;
    if (t < HID){
      short h, l; fsplit(W_gat[(size_t)k*HID + t], h, l);
      wtg_hi[t*HID + k] = h; wtg_lo[t*HID + k] = l;
    }
  } else if (bid <= 384){
    int i = (bid-129)*256 + t;          // 0..65535 = 64*1024
    short h, l; fsplit(lm[i], h, l);
    lmb_hi[i] = h; lmb_lo[i] = l;
  } else if (bid <= 510){
    int i = (bid-385)*256 + t;
    if (i < NN){ deg[i]=0; asum[i]=0.f; }
    if (i == 0) counter[0]=0;
  } else {
    int b = bid - 511;                   // 0..63
    if (t < HID){
      const float* lr_ = lm + (size_t)b*LMD;
      float s = b_lm[t];
      for (int l=0;l<LMD;++l) s += lr_[l]*W_lm[(size_t)l*HID + t];
      ctx_emb[b*HID + t] = s;
    }
  }
}

__global__ void k_count(const int* __restrict__ dst, const int* __restrict__ et,
                        const float* __restrict__ te, int* __restrict__ deg,
                        float* __restrict__ asum, int E){
  int e = blockIdx.x*256 + threadIdx.x;
  if (e >= E) return;
  int d = dst[e];
  atomicAdd(&deg[d], 1);
  atomicAdd(&asum[d], te[et[e]]);
}

__global__ void k_offsets(const int* __restrict__ deg, const float* __restrict__ asum,
                          int* __restrict__ off, int* __restrict__ cursor,
                          float* __restrict__ aself, int* __restrict__ counter){
  int i = blockIdx.x*256 + threadIdx.x;
  if (i >= NN) return;
  int d = deg[i];
  int o = atomicAdd(counter, d);
  off[i] = o; cursor[i] = o;
  aself[i] = asum[i] / (float)(d > 1 ? d : 1);
}

__global__ void k_fill(const int* __restrict__ src, const int* __restrict__ dst,
                       const int* __restrict__ et, const float* __restrict__ te,
                       int* __restrict__ cursor, int* __restrict__ csr_src,
                       float* __restrict__ csr_aed, int E){
  int e = blockIdx.x*256 + threadIdx.x;
  if (e >= E) return;
  int d = dst[e];
  int pos = atomicAdd(&cursor[d], 1);
  csr_src[pos] = src[e];
  csr_aed[pos] = te[et[e]];
}

// tmp[b,k,h] = sum_l lm[b,l]*W_bil[k,l,h] via split-bf16 MFMA (3 mfma ~ f32 precision)
__global__ __launch_bounds__(256) void k_tmp(const short* __restrict__ lmb_hi,
                                             const short* __restrict__ lmb_lo,
                                             const float* __restrict__ W_bil,
                                             float* __restrict__ tmp01,
                                             float* __restrict__ tmp23){
  const int kk = blockIdx.x >> 2;
  const int lq = blockIdx.x & 3;
  const int lbase = lq*256;
  __shared__ short Bh[128*36];
  __shared__ short Bl[128*36];
  const int tid = threadIdx.x;
  const int ln = tid & 63, wv = tid >> 6;
  const int lr = ln & 15, lk = ln >> 4;
  f32x4 acc[8];
  #pragma unroll
  for (int i=0;i<8;++i) acc[i] = (f32x4){0.f,0.f,0.f,0.f};
  bf16x8 ah[8], al[8];
  {
    const short* ap = lmb_hi + (size_t)(wv*16 + lr)*LMD + lbase + lk*8;
    const short* aq = lmb_lo + (size_t)(wv*16 + lr)*LMD + lbase + lk*8;
    #pragma unroll
    for (int ks=0;ks<8;++ks){ ah[ks] = *(const bf16x8*)(ap + ks*32);
                              al[ks] = *(const bf16x8*)(aq + ks*32); }
  }
  const int hb = tid & 7, lrow = tid >> 3;   // loader: h=(hb+8j), l=lrow
  const float* wp = W_bil + ((size_t)kk*LMD + lbase + lrow)*HID + hb;
  for (int ks=0; ks<8; ++ks){
    __syncthreads();
    #pragma unroll
    for (int j=0;j<16;++j){
      short h, l; fsplit(wp[(size_t)ks*32*HID + 8*j], h, l);
      Bh[(hb + 8*j)*36 + lrow] = h;
      Bl[(hb + 8*j)*36 + lrow] = l;
    }
    __syncthreads();
    #pragma unroll
    for (int ct=0; ct<8; ++ct){
      const int bo = (ct*16 + lr)*36 + lk*8;
      bf16x4 h0 = *(const bf16x4*)&Bh[bo];
      bf16x4 h1 = *(const bf16x4*)&Bh[bo+4];
      bf16x4 l0 = *(const bf16x4*)&Bl[bo];
      bf16x4 l1 = *(const bf16x4*)&Bl[bo+4];
      bf16x8 bh, bl;
      bh[0]=h0[0];bh[1]=h0[1];bh[2]=h0[2];bh[3]=h0[3];
      bh[4]=h1[0];bh[5]=h1[1];bh[6]=h1[2];bh[7]=h1[3];
      bl[0]=l0[0];bl[1]=l0[1];bl[2]=l0[2];bl[3]=l0[3];
      bl[4]=l1[0];bl[5]=l1[1];bl[6]=l1[2];bl[7]=l1[3];
      acc[ct] = __builtin_amdgcn_mfma_f32_16x16x32_bf16(ah[ks], bh, acc[ct], 0, 0, 0);
      acc[ct] = __builtin_amdgcn_mfma_f32_16x16x32_bf16(ah[ks], bl, acc[ct], 0, 0, 0);
      acc[ct] = __builtin_amdgcn_mfma_f32_16x16x32_bf16(al[ks], bh, acc[ct], 0, 0, 0);
    }
  }
  float* out = (lq < 2) ? (tmp01 + (size_t)lq*TPART) : (tmp23 + (size_t)(lq-2)*TPART);
  const int brow = wv*16 + lk*4;
  #pragma unroll
  for (int ct=0; ct<8; ++ct){
    int h = ct*16 + lr;
    #pragma unroll
    for (int j=0;j<4;++j)
      out[ ((size_t)(brow + j)*HID + kk)*HID + h ] = acc[ct][j];
  }
}

// nodes[g*NPG+n, k] = sum_h (4 tmp partials)[g,k,h]*x[g,n,h] + b_bil[k]
__global__ __launch_bounds__(256) void k_apply(const float* __restrict__ node_emb,
                                               const float* __restrict__ ctx_emb,
                                               const float* __restrict__ tmp01,
                                               const float* __restrict__ tmp23,
                                               const float* __restrict__ b_bil,
                                               float* __restrict__ nodes){
  const int bid = blockIdx.x;
  const int g  = bid >> 4;
  const int rt = (bid >> 1) & 7;
  const int kt = bid & 1;
  const int n0 = rt*64, k0 = kt*64;
  __shared__ float As[32][65];
  __shared__ float Bs[32][65];
  const int tid = threadIdx.x, ty = tid>>4, tx = tid&15;
  float acc[4][4] = {};
  const int lr = tid >> 2, lc = (tid & 3) * 8;
  const float* xrow = nullptr;
  {
    int nl = n0 + lr;
    if (nl < NPG) xrow = (nl == 0) ? (ctx_emb + (size_t)g*HID)
                                   : (node_emb + ((size_t)(g*NPG + nl))*HID);
  }
  const float* pA = tmp01 + ((size_t)(g*HID + k0 + lr))*HID;
  const float* pB = pA + TPART;
  const float* pC = tmp23 + ((size_t)(g*HID + k0 + lr))*HID;
  const float* pD = pC + TPART;
  for (int h0c = 0; h0c < HID; h0c += 32){
    #pragma unroll
    for (int j=0;j<8;++j) As[lc+j][lr] = xrow ? xrow[h0c + lc + j] : 0.f;
    #pragma unroll
    for (int j=0;j<8;++j) Bs[lc+j][lr] = pA[h0c+lc+j] + pB[h0c+lc+j] + pC[h0c+lc+j] + pD[h0c+lc+j];
    __syncthreads();
    #pragma unroll
    for (int hc=0;hc<32;++hc){
      float a[4], b[4];
      #pragma unroll
      for (int i=0;i<4;++i) a[i] = As[hc][ty*4+i];
      #pragma unroll
      for (int j=0;j<4;++j) b[j] = Bs[hc][tx*4+j];
      #pragma unroll
      for (int i=0;i<4;++i)
        #pragma unroll
        for (int j=0;j<4;++j) acc[i][j] += a[i]*b[j];
    }
    __syncthreads();
  }
  float bb[4];
  #pragma unroll
  for (int j=0;j<4;++j) bb[j] = b_bil[k0 + tx*4 + j];
  #pragma unroll
  for (int i=0;i<4;++i){
    int nl = n0 + ty*4 + i;
    if (nl < NPG){
      float* o = nodes + ((size_t)(g*NPG + nl))*HID + k0 + tx*4;
      #pragma unroll
      for (int j=0;j<4;++j) o[j] = acc[i][j] + bb[j];
    }
  }
}

// xl = nodes @ W_gat via split-bf16 MFMA; as/ad fused epilogue. 64 rows/block.
#define LDB 140
__global__ __launch_bounds__(256) void k_xl(const float* __restrict__ nodes,
                                            const short* __restrict__ wtg_hi,
                                            const short* __restrict__ wtg_lo,
                                            const float* __restrict__ att_src,
                                            const float* __restrict__ att_dst,
                                            float* __restrict__ xl,
                                            float* __restrict__ as_a,
                                            float* __restrict__ ad_a){
  __shared__ short Bth[128*LDB];
  __shared__ short Btl[128*LDB];
  const int tid = threadIdx.x;
  {
    int n = tid >> 1, half = tid & 1;
    const bf16x4* sh = (const bf16x4*)(wtg_hi + n*HID + half*64);
    const bf16x4* sl = (const bf16x4*)(wtg_lo + n*HID + half*64);
    short* dh = &Bth[n*LDB + half*64];
    short* dl = &Btl[n*LDB + half*64];
    #pragma unroll
    for (int i=0;i<16;++i){ *(bf16x4*)(dh + i*4) = sh[i]; *(bf16x4*)(dl + i*4) = sl[i]; }
  }
  __syncthreads();
  const int ln = tid & 63, wv = tid >> 6;
  const int lr = ln & 15, lk = ln >> 4;
  const int row0 = blockIdx.x*64 + wv*16;
  bf16x8 ah[4], al[4];
  {
    int r = row0 + lr;
    if (r >= NN) r = NN-1;
    const float* ap = nodes + (size_t)r*HID + lk*8;
    #pragma unroll
    for (int ks=0;ks<4;++ks){
      float4 x0 = *(const float4*)(ap + ks*32);
      float4 x1 = *(const float4*)(ap + ks*32 + 4);
      bf16x8 fh, fl;
      short h, l;
      fsplit(x0.x,h,l); fh[0]=h; fl[0]=l;
      fsplit(x0.y,h,l); fh[1]=h; fl[1]=l;
      fsplit(x0.z,h,l); fh[2]=h; fl[2]=l;
      fsplit(x0.w,h,l); fh[3]=h; fl[3]=l;
      fsplit(x1.x,h,l); fh[4]=h; fl[4]=l;
      fsplit(x1.y,h,l); fh[5]=h; fl[5]=l;
      fsplit(x1.z,h,l); fh[6]=h; fl[6]=l;
      fsplit(x1.w,h,l); fh[7]=h; fl[7]=l;
      ah[ks]=fh; al[ks]=fl;
    }
  }
  f32x4 acc[8];
  #pragma unroll
  for (int ct=0;ct<8;++ct) acc[ct] = (f32x4){0.f,0.f,0.f,0.f};
  #pragma unroll
  for (int ct=0;ct<8;++ct){
    #pragma unroll
    for (int ks=0;ks<4;++ks){
      const int bo = (ct*16+lr)*LDB + ks*32 + lk*8;
      bf16x4 h0 = *(const bf16x4*)&Bth[bo];
      bf16x4 h1 = *(const bf16x4*)&Bth[bo+4];
      bf16x4 l0 = *(const bf16x4*)&Btl[bo];
      bf16x4 l1 = *(const bf16x4*)&Btl[bo+4];
      bf16x8 bh, bl;
      bh[0]=h0[0];bh[1]=h0[1];bh[2]=h0[2];bh[3]=h0[3];
      bh[4]=h1[0];bh[5]=h1[1];bh[6]=h1[2];bh[7]=h1[3];
      bl[0]=l0[0];bl[1]=l0[1];bl[2]=l0[2];bl[3]=l0[3];
      bl[4]=l1[0];bl[5]=l1[1];bl[6]=l1[2];bl[7]=l1[3];
      acc[ct] = __builtin_amdgcn_mfma_f32_16x16x32_bf16(ah[ks], bh, acc[ct], 0, 0, 0);
      acc[ct] = __builtin_amdgcn_mfma_f32_16x16x32_bf16(ah[ks], bl, acc[ct], 0, 0, 0);
      acc[ct] = __builtin_amdgcn_mfma_f32_16x16x32_bf16(al[ks], bh, acc[ct], 0, 0, 0);
    }
  }
  float asv[8], adv[8];
  #pragma unroll
  for (int ct=0;ct<8;++ct){ asv[ct]=att_src[ct*16+lr]; adv[ct]=att_dst[ct*16+lr]; }
  #pragma unroll
  for (int j=0;j<4;++j){
    int r = row0 + lk*4 + j;
    float ps=0.f, pd=0.f;
    #pragma unroll
    for (int ct=0;ct<8;++ct){
      float v = acc[ct][j];
      ps += v*asv[ct]; pd += v*adv[ct];
      if (r < NN) xl[(size_t)r*HID + ct*16 + lr] = v;
    }
    #pragma unroll
    for (int msk=8;msk>=1;msk>>=1){ ps += __shfl_xor(ps,msk); pd += __shfl_xor(pd,msk); }
    if (lr == 0 && r < NN){ as_a[r]=ps; ad_a[r]=pd; }
  }
}

// per-node softmax aggregation, XCD-swizzled
__global__ __launch_bounds__(256) void k_agg(const float* __restrict__ xl,
                                             const float* __restrict__ as_a,
                                             const float* __restrict__ ad_a,
                                             const float* __restrict__ aself,
                                             const int* __restrict__ off,
                                             const int* __restrict__ deg,
                                             const int* __restrict__ csr_src,
                                             const float* __restrict__ csr_aed,
                                             const float* __restrict__ gbias,
                                             float* __restrict__ nodes){
  const int lane = threadIdx.x & 63;
  const int nb = blockIdx.x;
  const int idx = (nb & 7)*1002 + (nb >> 3);
  const int n = idx*4 + (threadIdx.x >> 6);
  if (n >= NN) return;
  const int o = off[n], d = deg[n];
  const float ad_n = ad_a[n];
  float a_self = as_a[n] + ad_n + aself[n];
  a_self = a_self > 0.f ? a_self : a_self*NEG;
  float m = -1e30f, s = 0.f;
  for (int i = lane; i < d; i += 64){
    int si = csr_src[o+i];
    float a = as_a[si] + ad_n + csr_aed[o+i];
    a = a > 0.f ? a : a*NEG;
    if (a > m){ s = s*__expf(m - a) + 1.f; m = a; }
    else s += __expf(a - m);
  }
  #pragma unroll
  for (int w=32; w>=1; w>>=1){
    float mo = __shfl_xor(m, w);
    float so = __shfl_xor(s, w);
    float M = fmaxf(m, mo);
    s = s*__expf(m - M) + so*__expf(mo - M);
    m = M;
  }
  { float M = fmaxf(m, a_self);
    s = s*__expf(m - M) + __expf(a_self - M);
    m = M; }
  const float inv = 1.f / s;
  float accx = 0.f, accy = 0.f;
  const float* xlane = xl + lane*2;
  for (int c = 0; c < d; c += 64){
    int i = c + lane;
    float w = 0.f; int si = 0;
    if (i < d){
      si = csr_src[o+i];
      float a = as_a[si] + ad_n + csr_aed[o+i];
      a = a > 0.f ? a : a*NEG;
      w = __expf(a - m)*inv;
    }
    const int cnt = (d - c) < 64 ? (d - c) : 64;
    int j = 0;
    for (; j + 4 <= cnt; j += 4){
      int   s0 = __shfl(si, j),   s1 = __shfl(si, j+1),
            s2 = __shfl(si, j+2), s3 = __shfl(si, j+3);
      float w0 = __shfl(w, j),    w1 = __shfl(w, j+1),
            w2 = __shfl(w, j+2),  w3 = __shfl(w, j+3);
      float2 v0 = *(const float2*)(xlane + (size_t)s0*HID);
      float2 v1 = *(const float2*)(xlane + (size_t)s1*HID);
      float2 v2 = *(const float2*)(xlane + (size_t)s2*HID);
      float2 v3 = *(const float2*)(xlane + (size_t)s3*HID);
      accx += w0*v0.x + w1*v1.x + w2*v2.x + w3*v3.x;
      accy += w0*v0.y + w1*v1.y + w2*v2.y + w3*v3.y;
    }
    for (; j < cnt; ++j){
      int   sj = __shfl(si, j);
      float wj = __shfl(w, j);
      float2 v = *(const float2*)(xlane + (size_t)sj*HID);
      accx += wj*v.x; accy += wj*v.y;
    }
  }
  { float w = __expf(a_self - m)*inv;
    const float2 v = *(const float2*)(xlane + (size_t)n*HID);
    accx += w*v.x; accy += w*v.y; }
  float2 ov;
  ov.x = accx + gbias[lane*2];
  ov.y = accy + gbias[lane*2+1];
  *(float2*)(nodes + (size_t)n*HID + lane*2) = ov;
}

__global__ void k_out(const float* __restrict__ nodes, const int* __restrict__ ctxn,
                      float* __restrict__ out){
  int b = blockIdx.x, h = threadIdx.x;
  out[b*HID + h] = nodes[(size_t)ctxn[b]*HID + h];
}

extern "C" void kernel_launch(void* const* d_in, const int* in_sizes, int n_in,
                              void* d_out, int out_size, void* d_ws, size_t ws_size,
                              hipStream_t stream){
  (void)n_in; (void)out_size; (void)ws_size;
  const float* lm       = (const float*)d_in[0];
  const float* node_emb = (const float*)d_in[1];
  const int*   eidx     = (const int*)d_in[2];
  const int*   etype    = (const int*)d_in[3];
  const int*   ctxn     = (const int*)d_in[4];
  const float* W_lm     = (const float*)d_in[5];
  const float* b_lm     = (const float*)d_in[6];
  const float* W_bil    = (const float*)d_in[7];
  const float* b_bil    = (const float*)d_in[8];
  const float* etab     = (const float*)d_in[9];
  const float* W_gat    = (const float*)d_in[10];
  const float* att_src  = (const float*)d_in[11];
  const float* att_dst  = (const float*)d_in[12];
  const float* W_edge   = (const float*)d_in[13];
  const float* att_edge = (const float*)d_in[14];
  const float* gbias    = (const float*)d_in[15];
  const int E = in_sizes[3];
  const int* src = eidx;
  const int* dst = eidx + E;

  char* p = (char*)d_ws;
  auto take = [&](size_t nbytes){ void* r = (void*)p; p += (nbytes + 255) & ~(size_t)255; return r; };
  float* nodes   = (float*)take((size_t)NN*HID*4);
  float* xl      = (float*)take((size_t)NN*HID*4);
  float* tmp01   = (float*)take((size_t)2*TPART*4);
  float* tmp23   = xl;                                  // alias: dead before k_xl
  float* ctx_emb = (float*)take((size_t)BGR*HID*4);
  float* as_a    = (float*)take((size_t)NN*4);
  float* ad_a    = (float*)take((size_t)NN*4);
  float* aself   = (float*)take((size_t)NN*4);
  float* asum    = (float*)take((size_t)NN*4);
  int*   deg     = (int*)take((size_t)NN*4);
  int*   off     = (int*)take((size_t)NN*4);
  int*   cursor  = (int*)take((size_t)NN*4);
  int*   counter = (int*)take(256);
  float* te      = (float*)take(256);
  int*   csr_src = (int*)take((size_t)E*4);
  float* csr_aed = (float*)take((size_t)E*4);
  short* lmb_hi  = (short*)take((size_t)BGR*LMD*2);
  short* lmb_lo  = (short*)take((size_t)BGR*LMD*2);
  short* wtg_hi  = (short*)take((size_t)HID*HID*2);
  short* wtg_lo  = (short*)take((size_t)HID*HID*2);

  k_setup<<<575,256,0,stream>>>(W_edge, att_edge, etab, te, W_gat, wtg_hi, wtg_lo,
                                lm, lmb_hi, lmb_lo, W_lm, b_lm, ctx_emb, deg, asum, counter);
  k_count<<<(E+255)/256,256,0,stream>>>(dst, etype, te, deg, asum, E);
  k_offsets<<<(NN+255)/256,256,0,stream>>>(deg, asum, off, cursor, aself, counter);
  k_fill<<<(E+255)/256,256,0,stream>>>(src, dst, etype, te, cursor, csr_src, csr_aed, E);
  k_tmp<<<512,256,0,stream>>>(lmb_hi, lmb_lo, W_bil, tmp01, tmp23);
  k_apply<<<BGR*16,256,0,stream>>>(node_emb, ctx_emb, tmp01, tmp23, b_bil, nodes);
  for (int h=0; h<3; ++h){
    k_xl<<<(NN+63)/64,256,0,stream>>>(nodes, wtg_hi, wtg_lo, att_src, att_dst, xl, as_a, ad_a);
    k_agg<<<NN/4,256,0,stream>>>(xl, as_a, ad_a, aself, off, deg, csr_src, csr_aed, gbias, nodes);
  }
  k_out<<<BGR,HID,0,stream>>>(nodes, ctxn, (float*)d_out);
}

// Round 5
// 412.126 us; speedup vs baseline: 1.2389x; 1.2389x over previous
//
#include <hip/hip_runtime.h>
#include <hip/hip_bf16.h>

#define HID 128
#define LMD 1024
#define BGR 64
#define NPG 501
#define NN (BGR*NPG)
#define NRELT 42
#define NEG 0.2f
#define TPART ((size_t)BGR*HID*HID)

typedef short bf16x8 __attribute__((ext_vector_type(8)));
typedef short bf16x4 __attribute__((ext_vector_type(4)));
typedef float f32x4  __attribute__((ext_vector_type(4)));

__device__ __forceinline__ short f2bf(float x){
  union { float f; unsigned u; } v; v.f = x;
  unsigned r = v.u + 0x7FFFu + ((v.u >> 16) & 1u);
  return (short)(r >> 16);
}
__device__ __forceinline__ float bf2f(short h){
  union { unsigned u; float f; } v; v.u = ((unsigned)(unsigned short)h) << 16;
  return v.f;
}
__device__ __forceinline__ void fsplit(float x, short& hi, short& lo){
  hi = f2bf(x);
  lo = f2bf(x - bf2f(hi));
}

// merged setup: te / W_gat^T->bf16 hi+lo / zero / ctx_emb
__global__ void k_setup(const float* __restrict__ W_edge, const float* __restrict__ att_edge,
                        const float* __restrict__ etab, float* __restrict__ te,
                        const float* __restrict__ W_gat, short* __restrict__ wtg_hi,
                        short* __restrict__ wtg_lo,
                        const float* __restrict__ lm,
                        const float* __restrict__ W_lm, const float* __restrict__ b_lm,
                        float* __restrict__ ctx_emb,
                        int* __restrict__ deg, float* __restrict__ asum,
                        int* __restrict__ counter){
  const int bid = blockIdx.x, t = threadIdx.x;
  if (bid == 0){
    __shared__ float we[HID];
    if (t < HID){
      float s = 0.f;
      for (int j=0;j<HID;++j) s += W_edge[t*HID+j]*att_edge[j];
      we[t] = s;
    }
    __syncthreads();
    if (t < NRELT){
      float s = 0.f;
      for (int i=0;i<HID;++i) s += etab[t*HID+i]*we[i];
      te[t] = s;
    }
  } else if (bid <= 128){
    int k = bid - 1;
    if (t < HID){
      short h, l; fsplit(W_gat[(size_t)k*HID + t], h, l);
      wtg_hi[t*HID + k] = h; wtg_lo[t*HID + k] = l;
    }
  } else if (bid <= 254){
    int i = (bid-129)*256 + t;
    if (i < NN){ deg[i]=0; asum[i]=0.f; }
    if (i == 0) counter[0]=0;
  } else {
    int b = bid - 255;                   // 0..63
    if (t < HID){
      const float* lr_ = lm + (size_t)b*LMD;
      float s = b_lm[t];
      for (int l=0;l<LMD;++l) s += lr_[l]*W_lm[(size_t)l*HID + t];
      ctx_emb[b*HID + t] = s;
    }
  }
}

__global__ void k_count(const int* __restrict__ dst, const int* __restrict__ et,
                        const float* __restrict__ te, int* __restrict__ deg,
                        float* __restrict__ asum, int E){
  int e = blockIdx.x*256 + threadIdx.x;
  if (e >= E) return;
  int d = dst[e];
  atomicAdd(&deg[d], 1);
  atomicAdd(&asum[d], te[et[e]]);
}

__global__ void k_offsets(const int* __restrict__ deg, const float* __restrict__ asum,
                          int* __restrict__ off, int* __restrict__ cursor,
                          float* __restrict__ aself, int* __restrict__ counter){
  int i = blockIdx.x*256 + threadIdx.x;
  if (i >= NN) return;
  int d = deg[i];
  int o = atomicAdd(counter, d);
  off[i] = o; cursor[i] = o;
  aself[i] = asum[i] / (float)(d > 1 ? d : 1);
}

__global__ void k_fill(const int* __restrict__ src, const int* __restrict__ dst,
                       const int* __restrict__ et, const float* __restrict__ te,
                       int* __restrict__ cursor, int* __restrict__ csr_src,
                       float* __restrict__ csr_aed, int E){
  int e = blockIdx.x*256 + threadIdx.x;
  if (e >= E) return;
  int d = dst[e];
  int pos = atomicAdd(&cursor[d], 1);
  csr_src[pos] = src[e];
  csr_aed[pos] = te[et[e]];
}

// tmp[b,k,h] = sum_l lm[b,l]*W_bil[k,l,h]; f32 VALU GEMM.
// grid 1024: k = bid>>3, h0 = ((bid>>2)&1)*64, lq = bid&3 (l-quarter, 4 partials).
// Bs padded to 68: round-2's Bs[32][64] had an 8-way bank conflict on writes
// (row stride 64 words = 0 mod 32 banks; 524288 conflicts measured).
__global__ __launch_bounds__(256) void k_tmp(const float* __restrict__ lm,
                                             const float* __restrict__ W_bil,
                                             float* __restrict__ tmp01,
                                             float* __restrict__ tmp23){
  const int bid = blockIdx.x;
  const int k  = bid >> 3;
  const int h0 = ((bid >> 2) & 1) * 64;
  const int lq = bid & 3;
  const int lbase = lq * 256;
  __shared__ float As[32][65];
  __shared__ float Bs[32][68];
  const int tid = threadIdx.x;
  const int ty = tid >> 4, tx = tid & 15;
  float acc[4][4] = {};
  const float* __restrict__ Wk = W_bil + (size_t)k*LMD*HID;
  const int ar = tid >> 2, ac = (tid & 3) * 8;   // b, l-off
  const int br = tid >> 3, bc = (tid & 7) * 8;   // lc, h-off
  for (int l0 = 0; l0 < 256; l0 += 32){
    const int l = lbase + l0;
    #pragma unroll
    for (int j=0;j<8;++j) As[ac+j][ar] = lm[(size_t)ar*LMD + l + ac + j];
    #pragma unroll
    for (int j=0;j<8;++j) Bs[br][bc+j] = Wk[(size_t)(l + br)*HID + h0 + bc + j];
    __syncthreads();
    #pragma unroll
    for (int lc=0; lc<32; ++lc){
      float a[4], b[4];
      #pragma unroll
      for (int i=0;i<4;++i) a[i] = As[lc][ty*4+i];
      #pragma unroll
      for (int j=0;j<4;++j) b[j] = Bs[lc][tx*4+j];
      #pragma unroll
      for (int i=0;i<4;++i)
        #pragma unroll
        for (int j=0;j<4;++j) acc[i][j] += a[i]*b[j];
    }
    __syncthreads();
  }
  float* out = (lq < 2) ? (tmp01 + (size_t)lq*TPART) : (tmp23 + (size_t)(lq-2)*TPART);
  #pragma unroll
  for (int i=0;i<4;++i){
    int b = ty*4+i;
    float* o = out + ((size_t)b*HID + k)*HID + h0 + tx*4;
    #pragma unroll
    for (int j=0;j<4;++j) o[j] = acc[i][j];
  }
}

// nodes[g*NPG+n, k] = sum_h (4 tmp partials)[g,k,h]*x[g,n,h] + b_bil[k]
__global__ __launch_bounds__(256) void k_apply(const float* __restrict__ node_emb,
                                               const float* __restrict__ ctx_emb,
                                               const float* __restrict__ tmp01,
                                               const float* __restrict__ tmp23,
                                               const float* __restrict__ b_bil,
                                               float* __restrict__ nodes){
  const int bid = blockIdx.x;
  const int g  = bid >> 4;
  const int rt = (bid >> 1) & 7;
  const int kt = bid & 1;
  const int n0 = rt*64, k0 = kt*64;
  __shared__ float As[32][65];
  __shared__ float Bs[32][65];
  const int tid = threadIdx.x, ty = tid>>4, tx = tid&15;
  float acc[4][4] = {};
  const int lr = tid >> 2, lc = (tid & 3) * 8;
  const float* xrow = nullptr;
  {
    int nl = n0 + lr;
    if (nl < NPG) xrow = (nl == 0) ? (ctx_emb + (size_t)g*HID)
                                   : (node_emb + ((size_t)(g*NPG + nl))*HID);
  }
  const float* pA = tmp01 + ((size_t)(g*HID + k0 + lr))*HID;
  const float* pB = pA + TPART;
  const float* pC = tmp23 + ((size_t)(g*HID + k0 + lr))*HID;
  const float* pD = pC + TPART;
  for (int h0c = 0; h0c < HID; h0c += 32){
    #pragma unroll
    for (int j=0;j<8;++j) As[lc+j][lr] = xrow ? xrow[h0c + lc + j] : 0.f;
    #pragma unroll
    for (int j=0;j<8;++j) Bs[lc+j][lr] = pA[h0c+lc+j] + pB[h0c+lc+j] + pC[h0c+lc+j] + pD[h0c+lc+j];
    __syncthreads();
    #pragma unroll
    for (int hc=0;hc<32;++hc){
      float a[4], b[4];
      #pragma unroll
      for (int i=0;i<4;++i) a[i] = As[hc][ty*4+i];
      #pragma unroll
      for (int j=0;j<4;++j) b[j] = Bs[hc][tx*4+j];
      #pragma unroll
      for (int i=0;i<4;++i)
        #pragma unroll
        for (int j=0;j<4;++j) acc[i][j] += a[i]*b[j];
    }
    __syncthreads();
  }
  float bb[4];
  #pragma unroll
  for (int j=0;j<4;++j) bb[j] = b_bil[k0 + tx*4 + j];
  #pragma unroll
  for (int i=0;i<4;++i){
    int nl = n0 + ty*4 + i;
    if (nl < NPG){
      float* o = nodes + ((size_t)(g*NPG + nl))*HID + k0 + tx*4;
      #pragma unroll
      for (int j=0;j<4;++j) o[j] = acc[i][j] + bb[j];
    }
  }
}

// xl = nodes @ W_gat via split-bf16 MFMA; as/ad fused epilogue. 64 rows/block.
#define LDB 140
__global__ __launch_bounds__(256) void k_xl(const float* __restrict__ nodes,
                                            const short* __restrict__ wtg_hi,
                                            const short* __restrict__ wtg_lo,
                                            const float* __restrict__ att_src,
                                            const float* __restrict__ att_dst,
                                            float* __restrict__ xl,
                                            float* __restrict__ as_a,
                                            float* __restrict__ ad_a){
  __shared__ short Bth[128*LDB];
  __shared__ short Btl[128*LDB];
  const int tid = threadIdx.x;
  {
    int n = tid >> 1, half = tid & 1;
    const bf16x4* sh = (const bf16x4*)(wtg_hi + n*HID + half*64);
    const bf16x4* sl = (const bf16x4*)(wtg_lo + n*HID + half*64);
    short* dh = &Bth[n*LDB + half*64];
    short* dl = &Btl[n*LDB + half*64];
    #pragma unroll
    for (int i=0;i<16;++i){ *(bf16x4*)(dh + i*4) = sh[i]; *(bf16x4*)(dl + i*4) = sl[i]; }
  }
  __syncthreads();
  const int ln = tid & 63, wv = tid >> 6;
  const int lr = ln & 15, lk = ln >> 4;
  const int row0 = blockIdx.x*64 + wv*16;
  bf16x8 ah[4], al[4];
  {
    int r = row0 + lr;
    if (r >= NN) r = NN-1;
    const float* ap = nodes + (size_t)r*HID + lk*8;
    #pragma unroll
    for (int ks=0;ks<4;++ks){
      float4 x0 = *(const float4*)(ap + ks*32);
      float4 x1 = *(const float4*)(ap + ks*32 + 4);
      bf16x8 fh, fl;
      short h, l;
      fsplit(x0.x,h,l); fh[0]=h; fl[0]=l;
      fsplit(x0.y,h,l); fh[1]=h; fl[1]=l;
      fsplit(x0.z,h,l); fh[2]=h; fl[2]=l;
      fsplit(x0.w,h,l); fh[3]=h; fl[3]=l;
      fsplit(x1.x,h,l); fh[4]=h; fl[4]=l;
      fsplit(x1.y,h,l); fh[5]=h; fl[5]=l;
      fsplit(x1.z,h,l); fh[6]=h; fl[6]=l;
      fsplit(x1.w,h,l); fh[7]=h; fl[7]=l;
      ah[ks]=fh; al[ks]=fl;
    }
  }
  f32x4 acc[8];
  #pragma unroll
  for (int ct=0;ct<8;++ct) acc[ct] = (f32x4){0.f,0.f,0.f,0.f};
  #pragma unroll
  for (int ct=0;ct<8;++ct){
    #pragma unroll
    for (int ks=0;ks<4;++ks){
      const int bo = (ct*16+lr)*LDB + ks*32 + lk*8;
      bf16x4 h0 = *(const bf16x4*)&Bth[bo];
      bf16x4 h1 = *(const bf16x4*)&Bth[bo+4];
      bf16x4 l0 = *(const bf16x4*)&Btl[bo];
      bf16x4 l1 = *(const bf16x4*)&Btl[bo+4];
      bf16x8 bh, bl;
      bh[0]=h0[0];bh[1]=h0[1];bh[2]=h0[2];bh[3]=h0[3];
      bh[4]=h1[0];bh[5]=h1[1];bh[6]=h1[2];bh[7]=h1[3];
      bl[0]=l0[0];bl[1]=l0[1];bl[2]=l0[2];bl[3]=l0[3];
      bl[4]=l1[0];bl[5]=l1[1];bl[6]=l1[2];bl[7]=l1[3];
      acc[ct] = __builtin_amdgcn_mfma_f32_16x16x32_bf16(ah[ks], bh, acc[ct], 0, 0, 0);
      acc[ct] = __builtin_amdgcn_mfma_f32_16x16x32_bf16(ah[ks], bl, acc[ct], 0, 0, 0);
      acc[ct] = __builtin_amdgcn_mfma_f32_16x16x32_bf16(al[ks], bh, acc[ct], 0, 0, 0);
    }
  }
  float asv[8], adv[8];
  #pragma unroll
  for (int ct=0;ct<8;++ct){ asv[ct]=att_src[ct*16+lr]; adv[ct]=att_dst[ct*16+lr]; }
  #pragma unroll
  for (int j=0;j<4;++j){
    int r = row0 + lk*4 + j;
    float ps=0.f, pd=0.f;
    #pragma unroll
    for (int ct=0;ct<8;++ct){
      float v = acc[ct][j];
      ps += v*asv[ct]; pd += v*adv[ct];
      if (r < NN) xl[(size_t)r*HID + ct*16 + lr] = v;
    }
    #pragma unroll
    for (int msk=8;msk>=1;msk>>=1){ ps += __shfl_xor(ps,msk); pd += __shfl_xor(pd,msk); }
    if (lr == 0 && r < NN){ as_a[r]=ps; ad_a[r]=pd; }
  }
}

// per-node softmax aggregation, XCD-swizzled
__global__ __launch_bounds__(256) void k_agg(const float* __restrict__ xl,
                                             const float* __restrict__ as_a,
                                             const float* __restrict__ ad_a,
                                             const float* __restrict__ aself,
                                             const int* __restrict__ off,
                                             const int* __restrict__ deg,
                                             const int* __restrict__ csr_src,
                                             const float* __restrict__ csr_aed,
                                             const float* __restrict__ gbias,
                                             float* __restrict__ nodes){
  const int lane = threadIdx.x & 63;
  const int nb = blockIdx.x;
  const int idx = (nb & 7)*1002 + (nb >> 3);
  const int n = idx*4 + (threadIdx.x >> 6);
  if (n >= NN) return;
  const int o = off[n], d = deg[n];
  const float ad_n = ad_a[n];
  float a_self = as_a[n] + ad_n + aself[n];
  a_self = a_self > 0.f ? a_self : a_self*NEG;
  float m = -1e30f, s = 0.f;
  for (int i = lane; i < d; i += 64){
    int si = csr_src[o+i];
    float a = as_a[si] + ad_n + csr_aed[o+i];
    a = a > 0.f ? a : a*NEG;
    if (a > m){ s = s*__expf(m - a) + 1.f; m = a; }
    else s += __expf(a - m);
  }
  #pragma unroll
  for (int w=32; w>=1; w>>=1){
    float mo = __shfl_xor(m, w);
    float so = __shfl_xor(s, w);
    float M = fmaxf(m, mo);
    s = s*__expf(m - M) + so*__expf(mo - M);
    m = M;
  }
  { float M = fmaxf(m, a_self);
    s = s*__expf(m - M) + __expf(a_self - M);
    m = M; }
  const float inv = 1.f / s;
  float accx = 0.f, accy = 0.f;
  const float* xlane = xl + lane*2;
  for (int c = 0; c < d; c += 64){
    int i = c + lane;
    float w = 0.f; int si = 0;
    if (i < d){
      si = csr_src[o+i];
      float a = as_a[si] + ad_n + csr_aed[o+i];
      a = a > 0.f ? a : a*NEG;
      w = __expf(a - m)*inv;
    }
    const int cnt = (d - c) < 64 ? (d - c) : 64;
    int j = 0;
    for (; j + 4 <= cnt; j += 4){
      int   s0 = __shfl(si, j),   s1 = __shfl(si, j+1),
            s2 = __shfl(si, j+2), s3 = __shfl(si, j+3);
      float w0 = __shfl(w, j),    w1 = __shfl(w, j+1),
            w2 = __shfl(w, j+2),  w3 = __shfl(w, j+3);
      float2 v0 = *(const float2*)(xlane + (size_t)s0*HID);
      float2 v1 = *(const float2*)(xlane + (size_t)s1*HID);
      float2 v2 = *(const float2*)(xlane + (size_t)s2*HID);
      float2 v3 = *(const float2*)(xlane + (size_t)s3*HID);
      accx += w0*v0.x + w1*v1.x + w2*v2.x + w3*v3.x;
      accy += w0*v0.y + w1*v1.y + w2*v2.y + w3*v3.y;
    }
    for (; j < cnt; ++j){
      int   sj = __shfl(si, j);
      float wj = __shfl(w, j);
      float2 v = *(const float2*)(xlane + (size_t)sj*HID);
      accx += wj*v.x; accy += wj*v.y;
    }
  }
  { float w = __expf(a_self - m)*inv;
    const float2 v = *(const float2*)(xlane + (size_t)n*HID);
    accx += w*v.x; accy += w*v.y; }
  float2 ov;
  ov.x = accx + gbias[lane*2];
  ov.y = accy + gbias[lane*2+1];
  *(float2*)(nodes + (size_t)n*HID + lane*2) = ov;
}

__global__ void k_out(const float* __restrict__ nodes, const int* __restrict__ ctxn,
                      float* __restrict__ out){
  int b = blockIdx.x, h = threadIdx.x;
  out[b*HID + h] = nodes[(size_t)ctxn[b]*HID + h];
}

extern "C" void kernel_launch(void* const* d_in, const int* in_sizes, int n_in,
                              void* d_out, int out_size, void* d_ws, size_t ws_size,
                              hipStream_t stream){
  (void)n_in; (void)out_size; (void)ws_size;
  const float* lm       = (const float*)d_in[0];
  const float* node_emb = (const float*)d_in[1];
  const int*   eidx     = (const int*)d_in[2];
  const int*   etype    = (const int*)d_in[3];
  const int*   ctxn     = (const int*)d_in[4];
  const float* W_lm     = (const float*)d_in[5];
  const float* b_lm     = (const float*)d_in[6];
  const float* W_bil    = (const float*)d_in[7];
  const float* b_bil    = (const float*)d_in[8];
  const float* etab     = (const float*)d_in[9];
  const float* W_gat    = (const float*)d_in[10];
  const float* att_src  = (const float*)d_in[11];
  const float* att_dst  = (const float*)d_in[12];
  const float* W_edge   = (const float*)d_in[13];
  const float* att_edge = (const float*)d_in[14];
  const float* gbias    = (const float*)d_in[15];
  const int E = in_sizes[3];
  const int* src = eidx;
  const int* dst = eidx + E;

  char* p = (char*)d_ws;
  auto take = [&](size_t nbytes){ void* r = (void*)p; p += (nbytes + 255) & ~(size_t)255; return r; };
  float* nodes   = (float*)take((size_t)NN*HID*4);
  float* xl      = (float*)take((size_t)NN*HID*4);
  float* tmp01   = (float*)take((size_t)2*TPART*4);
  float* tmp23   = xl;                                  // alias: dead before k_xl
  float* ctx_emb = (float*)take((size_t)BGR*HID*4);
  float* as_a    = (float*)take((size_t)NN*4);
  float* ad_a    = (float*)take((size_t)NN*4);
  float* aself   = (float*)take((size_t)NN*4);
  float* asum    = (float*)take((size_t)NN*4);
  int*   deg     = (int*)take((size_t)NN*4);
  int*   off     = (int*)take((size_t)NN*4);
  int*   cursor  = (int*)take((size_t)NN*4);
  int*   counter = (int*)take(256);
  float* te      = (float*)take(256);
  int*   csr_src = (int*)take((size_t)E*4);
  float* csr_aed = (float*)take((size_t)E*4);
  short* wtg_hi  = (short*)take((size_t)HID*HID*2);
  short* wtg_lo  = (short*)take((size_t)HID*HID*2);

  k_setup<<<319,256,0,stream>>>(W_edge, att_edge, etab, te, W_gat, wtg_hi, wtg_lo,
                                lm, W_lm, b_lm, ctx_emb, deg, asum, counter);
  k_count<<<(E+255)/256,256,0,stream>>>(dst, etype, te, deg, asum, E);
  k_offsets<<<(NN+255)/256,256,0,stream>>>(deg, asum, off, cursor, aself, counter);
  k_fill<<<(E+255)/256,256,0,stream>>>(src, dst, etype, te, cursor, csr_src, csr_aed, E);
  k_tmp<<<1024,256,0,stream>>>(lm, W_bil, tmp01, tmp23);
  k_apply<<<BGR*16,256,0,stream>>>(node_emb, ctx_emb, tmp01, tmp23, b_bil, nodes);
  for (int h=0; h<3; ++h){
    k_xl<<<(NN+63)/64,256,0,stream>>>(nodes, wtg_hi, wtg_lo, att_src, att_dst, xl, as_a, ad_a);
    k_agg<<<NN/4,256,0,stream>>>(xl, as_a, ad_a, aself, off, deg, csr_src, csr_aed, gbias, nodes);
  }
  k_out<<<BGR,HID,0,stream>>>(nodes, ctxn, (float*)d_out);
}

// Round 7
// 375.500 us; speedup vs baseline: 1.3598x; 1.0975x over previous
//
#include <hip/hip_runtime.h>
#include <hip/hip_bf16.h>

#define HID 128
#define LMD 1024
#define BGR 64
#define NPG 501
#define NN (BGR*NPG)
#define NRELT 42
#define NEG 0.2f
#define TPART ((size_t)BGR*HID*HID)

typedef short bf16x8 __attribute__((ext_vector_type(8)));
typedef short bf16x4 __attribute__((ext_vector_type(4)));
typedef float f32x4  __attribute__((ext_vector_type(4)));

__device__ __forceinline__ short f2bf(float x){
  union { float f; unsigned u; } v; v.f = x;
  unsigned r = v.u + 0x7FFFu + ((v.u >> 16) & 1u);
  return (short)(r >> 16);
}
__device__ __forceinline__ float bf2f(short h){
  union { unsigned u; float f; } v; v.u = ((unsigned)(unsigned short)h) << 16;
  return v.f;
}
__device__ __forceinline__ void fsplit(float x, short& hi, short& lo){
  hi = f2bf(x);
  lo = f2bf(x - bf2f(hi));
}

// merged setup: te / W_gat^T->bf16 hi+lo / lm->bf16 hi+lo / zero / ctx_emb
__global__ void k_setup(const float* __restrict__ W_edge, const float* __restrict__ att_edge,
                        const float* __restrict__ etab, float* __restrict__ te,
                        const float* __restrict__ W_gat, short* __restrict__ wtg_hi,
                        short* __restrict__ wtg_lo,
                        const float* __restrict__ lm, short* __restrict__ lmb_hi,
                        short* __restrict__ lmb_lo,
                        const float* __restrict__ W_lm, const float* __restrict__ b_lm,
                        float* __restrict__ ctx_emb,
                        int* __restrict__ deg, float* __restrict__ asum,
                        int* __restrict__ counter){
  const int bid = blockIdx.x, t = threadIdx.x;
  if (bid == 0){
    __shared__ float we[HID];
    if (t < HID){
      float s = 0.f;
      for (int j=0;j<HID;++j) s += W_edge[t*HID+j]*att_edge[j];
      we[t] = s;
    }
    __syncthreads();
    if (t < NRELT){
      float s = 0.f;
      for (int i=0;i<HID;++i) s += etab[t*HID+i]*we[i];
      te[t] = s;
    }
  } else if (bid <= 128){
    int k = bid - 1;
    if (t < HID){
      short h, l; fsplit(W_gat[(size_t)k*HID + t], h, l);
      wtg_hi[t*HID + k] = h; wtg_lo[t*HID + k] = l;
    }
  } else if (bid <= 384){
    int i = (bid-129)*256 + t;          // 0..65535 = 64*1024
    short h, l; fsplit(lm[i], h, l);
    lmb_hi[i] = h; lmb_lo[i] = l;
  } else if (bid <= 510){
    int i = (bid-385)*256 + t;
    if (i < NN){ deg[i]=0; asum[i]=0.f; }
    if (i == 0) counter[0]=0;
  } else {
    int b = bid - 511;                   // 0..63
    if (t < HID){
      const float* lr_ = lm + (size_t)b*LMD;
      float s = b_lm[t];
      for (int l=0;l<LMD;++l) s += lr_[l]*W_lm[(size_t)l*HID + t];
      ctx_emb[b*HID + t] = s;
    }
  }
}

__global__ void k_count(const int* __restrict__ dst, const int* __restrict__ et,
                        const float* __restrict__ te, int* __restrict__ deg,
                        float* __restrict__ asum, int E){
  int e = blockIdx.x*256 + threadIdx.x;
  if (e >= E) return;
  int d = dst[e];
  atomicAdd(&deg[d], 1);
  atomicAdd(&asum[d], te[et[e]]);
}

__global__ void k_offsets(const int* __restrict__ deg, const float* __restrict__ asum,
                          int* __restrict__ off, int* __restrict__ cursor,
                          float* __restrict__ aself, int* __restrict__ counter){
  int i = blockIdx.x*256 + threadIdx.x;
  if (i >= NN) return;
  int d = deg[i];
  int o = atomicAdd(counter, d);
  off[i] = o; cursor[i] = o;
  aself[i] = asum[i] / (float)(d > 1 ? d : 1);
}

__global__ void k_fill(const int* __restrict__ src, const int* __restrict__ dst,
                       const int* __restrict__ et, const float* __restrict__ te,
                       int* __restrict__ cursor, int* __restrict__ csr_src,
                       float* __restrict__ csr_aed, int E){
  int e = blockIdx.x*256 + threadIdx.x;
  if (e >= E) return;
  int d = dst[e];
  int pos = atomicAdd(&cursor[d], 1);
  csr_src[pos] = src[e];
  csr_aed[pos] = te[et[e]];
}

// tmp[b,k,h] = sum_l lm[b,l]*W_bil[k,l,h] via split-bf16 MFMA, v2:
// B staged to LDS in fragment-major layout (one ds_read_b128 per fragment,
// no per-element assembly — round 4's 55% VALU / 1.7% MfmaUtil failure mode).
// A (lm hi/lo) read from pre-split global into registers. Grid 512: k=bid>>2,
// lq=bid&3 (l-quarter partial). 4 chunks of 64 l per block; LDS 36 KB.
__global__ __launch_bounds__(256) void k_tmp(const short* __restrict__ lmb_hi,
                                             const short* __restrict__ lmb_lo,
                                             const float* __restrict__ W_bil,
                                             float* __restrict__ tmp01,
                                             float* __restrict__ tmp23){
  const int k  = blockIdx.x >> 2;
  const int lq = blockIdx.x & 3;
  const int lbase = lq*256;
  __shared__ short Bhi[128*72];   // Bhi[h][l'], row stride 72 shorts (144B)
  __shared__ short Blo[128*72];
  const int tid = threadIdx.x;
  const int ln = tid & 63, wv = tid >> 6;
  const int lr = ln & 15, lk = ln >> 4;
  const int h  = tid & 127, half = tid >> 7;
  f32x4 acc[8];
  #pragma unroll
  for (int i=0;i<8;++i) acc[i] = (f32x4){0.f,0.f,0.f,0.f};
  for (int c=0;c<4;++c){
    if (c) __syncthreads();
    // stage: thread reads 8-l' columns of one h (256B-coalesced across wave)
    const float* wp = W_bil + ((size_t)k*LMD + lbase + c*64)*HID + h;
    #pragma unroll
    for (int p=0;p<4;++p){
      const int q = half + 2*p;          // l'-group 0..7
      bf16x8 hi8, lo8;
      #pragma unroll
      for (int i=0;i<8;++i){
        short h_, l_; fsplit(wp[(size_t)(q*8+i)*HID], h_, l_);
        hi8[i]=h_; lo8[i]=l_;
      }
      *(bf16x8*)&Bhi[h*72 + q*8] = hi8;
      *(bf16x8*)&Blo[h*72 + q*8] = lo8;
    }
    __syncthreads();
    #pragma unroll
    for (int ks=0;ks<2;++ks){
      const size_t aoff = (size_t)(wv*16+lr)*LMD + lbase + c*64 + ks*32 + lk*8;
      bf16x8 ah = *(const bf16x8*)(lmb_hi + aoff);
      bf16x8 al = *(const bf16x8*)(lmb_lo + aoff);
      #pragma unroll
      for (int ct=0;ct<8;++ct){
        const int bo = (ct*16+lr)*72 + ks*32 + lk*8;
        bf16x8 bh = *(const bf16x8*)&Bhi[bo];
        bf16x8 bl = *(const bf16x8*)&Blo[bo];
        acc[ct] = __builtin_amdgcn_mfma_f32_16x16x32_bf16(ah, bh, acc[ct], 0, 0, 0);
        acc[ct] = __builtin_amdgcn_mfma_f32_16x16x32_bf16(ah, bl, acc[ct], 0, 0, 0);
        acc[ct] = __builtin_amdgcn_mfma_f32_16x16x32_bf16(al, bh, acc[ct], 0, 0, 0);
      }
    }
  }
  float* out = (lq < 2) ? (tmp01 + (size_t)lq*TPART) : (tmp23 + (size_t)(lq-2)*TPART);
  const int brow = wv*16 + lk*4;
  #pragma unroll
  for (int ct=0; ct<8; ++ct){
    int hh = ct*16 + lr;
    #pragma unroll
    for (int j=0;j<4;++j)
      out[ ((size_t)(brow + j)*HID + k)*HID + hh ] = acc[ct][j];
  }
}

// nodes[g*NPG+n, k] = sum_h (4 tmp partials)[g,k,h]*x[g,n,h] + b_bil[k]
__global__ __launch_bounds__(256) void k_apply(const float* __restrict__ node_emb,
                                               const float* __restrict__ ctx_emb,
                                               const float* __restrict__ tmp01,
                                               const float* __restrict__ tmp23,
                                               const float* __restrict__ b_bil,
                                               float* __restrict__ nodes){
  const int bid = blockIdx.x;
  const int g  = bid >> 4;
  const int rt = (bid >> 1) & 7;
  const int kt = bid & 1;
  const int n0 = rt*64, k0 = kt*64;
  __shared__ float As[32][65];
  __shared__ float Bs[32][65];
  const int tid = threadIdx.x, ty = tid>>4, tx = tid&15;
  float acc[4][4] = {};
  const int lr = tid >> 2, lc = (tid & 3) * 8;
  const float* xrow = nullptr;
  {
    int nl = n0 + lr;
    if (nl < NPG) xrow = (nl == 0) ? (ctx_emb + (size_t)g*HID)
                                   : (node_emb + ((size_t)(g*NPG + nl))*HID);
  }
  const float* pA = tmp01 + ((size_t)(g*HID + k0 + lr))*HID;
  const float* pB = pA + TPART;
  const float* pC = tmp23 + ((size_t)(g*HID + k0 + lr))*HID;
  const float* pD = pC + TPART;
  for (int h0c = 0; h0c < HID; h0c += 32){
    #pragma unroll
    for (int j=0;j<8;++j) As[lc+j][lr] = xrow ? xrow[h0c + lc + j] : 0.f;
    #pragma unroll
    for (int j=0;j<8;++j) Bs[lc+j][lr] = pA[h0c+lc+j] + pB[h0c+lc+j] + pC[h0c+lc+j] + pD[h0c+lc+j];
    __syncthreads();
    #pragma unroll
    for (int hc=0;hc<32;++hc){
      float a[4], b[4];
      #pragma unroll
      for (int i=0;i<4;++i) a[i] = As[hc][ty*4+i];
      #pragma unroll
      for (int j=0;j<4;++j) b[j] = Bs[hc][tx*4+j];
      #pragma unroll
      for (int i=0;i<4;++i)
        #pragma unroll
        for (int j=0;j<4;++j) acc[i][j] += a[i]*b[j];
    }
    __syncthreads();
  }
  float bb[4];
  #pragma unroll
  for (int j=0;j<4;++j) bb[j] = b_bil[k0 + tx*4 + j];
  #pragma unroll
  for (int i=0;i<4;++i){
    int nl = n0 + ty*4 + i;
    if (nl < NPG){
      float* o = nodes + ((size_t)(g*NPG + nl))*HID + k0 + tx*4;
      #pragma unroll
      for (int j=0;j<4;++j) o[j] = acc[i][j] + bb[j];
    }
  }
}

// xl = nodes @ W_gat via split-bf16 MFMA; as/ad fused epilogue. 64 rows/block.
#define LDB 140
__global__ __launch_bounds__(256) void k_xl(const float* __restrict__ nodes,
                                            const short* __restrict__ wtg_hi,
                                            const short* __restrict__ wtg_lo,
                                            const float* __restrict__ att_src,
                                            const float* __restrict__ att_dst,
                                            float* __restrict__ xl,
                                            float* __restrict__ as_a,
                                            float* __restrict__ ad_a){
  __shared__ short Bth[128*LDB];
  __shared__ short Btl[128*LDB];
  const int tid = threadIdx.x;
  {
    int n = tid >> 1, half = tid & 1;
    const bf16x4* sh = (const bf16x4*)(wtg_hi + n*HID + half*64);
    const bf16x4* sl = (const bf16x4*)(wtg_lo + n*HID + half*64);
    short* dh = &Bth[n*LDB + half*64];
    short* dl = &Btl[n*LDB + half*64];
    #pragma unroll
    for (int i=0;i<16;++i){ *(bf16x4*)(dh + i*4) = sh[i]; *(bf16x4*)(dl + i*4) = sl[i]; }
  }
  __syncthreads();
  const int ln = tid & 63, wv = tid >> 6;
  const int lr = ln & 15, lk = ln >> 4;
  const int row0 = blockIdx.x*64 + wv*16;
  bf16x8 ah[4], al[4];
  {
    int r = row0 + lr;
    if (r >= NN) r = NN-1;
    const float* ap = nodes + (size_t)r*HID + lk*8;
    #pragma unroll
    for (int ks=0;ks<4;++ks){
      float4 x0 = *(const float4*)(ap + ks*32);
      float4 x1 = *(const float4*)(ap + ks*32 + 4);
      bf16x8 fh, fl;
      short h, l;
      fsplit(x0.x,h,l); fh[0]=h; fl[0]=l;
      fsplit(x0.y,h,l); fh[1]=h; fl[1]=l;
      fsplit(x0.z,h,l); fh[2]=h; fl[2]=l;
      fsplit(x0.w,h,l); fh[3]=h; fl[3]=l;
      fsplit(x1.x,h,l); fh[4]=h; fl[4]=l;
      fsplit(x1.y,h,l); fh[5]=h; fl[5]=l;
      fsplit(x1.z,h,l); fh[6]=h; fl[6]=l;
      fsplit(x1.w,h,l); fh[7]=h; fl[7]=l;
      ah[ks]=fh; al[ks]=fl;
    }
  }
  f32x4 acc[8];
  #pragma unroll
  for (int ct=0;ct<8;++ct) acc[ct] = (f32x4){0.f,0.f,0.f,0.f};
  #pragma unroll
  for (int ct=0;ct<8;++ct){
    #pragma unroll
    for (int ks=0;ks<4;++ks){
      const int bo = (ct*16+lr)*LDB + ks*32 + lk*8;
      bf16x4 h0 = *(const bf16x4*)&Bth[bo];
      bf16x4 h1 = *(const bf16x4*)&Bth[bo+4];
      bf16x4 l0 = *(const bf16x4*)&Btl[bo];
      bf16x4 l1 = *(const bf16x4*)&Btl[bo+4];
      bf16x8 bh, bl;
      bh[0]=h0[0];bh[1]=h0[1];bh[2]=h0[2];bh[3]=h0[3];
      bh[4]=h1[0];bh[5]=h1[1];bh[6]=h1[2];bh[7]=h1[3];
      bl[0]=l0[0];bl[1]=l0[1];bl[2]=l0[2];bl[3]=l0[3];
      bl[4]=l1[0];bl[5]=l1[1];bl[6]=l1[2];bl[7]=l1[3];
      acc[ct] = __builtin_amdgcn_mfma_f32_16x16x32_bf16(ah[ks], bh, acc[ct], 0, 0, 0);
      acc[ct] = __builtin_amdgcn_mfma_f32_16x16x32_bf16(ah[ks], bl, acc[ct], 0, 0, 0);
      acc[ct] = __builtin_amdgcn_mfma_f32_16x16x32_bf16(al[ks], bh, acc[ct], 0, 0, 0);
    }
  }
  float asv[8], adv[8];
  #pragma unroll
  for (int ct=0;ct<8;++ct){ asv[ct]=att_src[ct*16+lr]; adv[ct]=att_dst[ct*16+lr]; }
  #pragma unroll
  for (int j=0;j<4;++j){
    int r = row0 + lk*4 + j;
    float ps=0.f, pd=0.f;
    #pragma unroll
    for (int ct=0;ct<8;++ct){
      float v = acc[ct][j];
      ps += v*asv[ct]; pd += v*adv[ct];
      if (r < NN) xl[(size_t)r*HID + ct*16 + lr] = v;
    }
    #pragma unroll
    for (int msk=8;msk>=1;msk>>=1){ ps += __shfl_xor(ps,msk); pd += __shfl_xor(pd,msk); }
    if (lr == 0 && r < NN){ as_a[r]=ps; ad_a[r]=pd; }
  }
}

// f32 xl for rows 0..10 of each graph only (hop 3 needs just these):
// writes xl rows, as_a, ad_a for those rows. One block per graph.
__global__ __launch_bounds__(256) void k_xl_small(const float* __restrict__ nodes,
                                                  const float* __restrict__ W_gat,
                                                  const float* __restrict__ att_src,
                                                  const float* __restrict__ att_dst,
                                                  float* __restrict__ xl,
                                                  float* __restrict__ as_a,
                                                  float* __restrict__ ad_a){
  const int g = blockIdx.x, t = threadIdx.x;
  __shared__ float sn[11][HID];
  __shared__ float sx[11][HID];
  for (int idx = t; idx < 11*HID; idx += 256)
    sn[idx>>7][idx&127] = nodes[((size_t)g*NPG + (idx>>7))*HID + (idx&127)];
  __syncthreads();
  for (int idx = t; idx < 11*HID; idx += 256){
    const int r = idx>>7, h = idx&127;
    float s = 0.f;
    #pragma unroll 8
    for (int l=0;l<HID;++l) s += sn[r][l]*W_gat[(size_t)l*HID + h];
    sx[r][h] = s;
    xl[((size_t)g*NPG + r)*HID + h] = s;
  }
  __syncthreads();
  const int ln = t & 63, wv = t >> 6;
  for (int r = wv; r < 11; r += 4){
    float v0 = sx[r][ln], v1 = sx[r][64+ln];
    float ps = v0*att_src[ln] + v1*att_src[64+ln];
    float pd = v0*att_dst[ln] + v1*att_dst[64+ln];
    #pragma unroll
    for (int msk=32;msk>=1;msk>>=1){ ps += __shfl_xor(ps,msk); pd += __shfl_xor(pd,msk); }
    if (ln == 0){ as_a[(size_t)g*NPG + r] = ps; ad_a[(size_t)g*NPG + r] = pd; }
  }
}

// per-node softmax-weighted aggregation core (one wave per node)
__device__ __forceinline__ void agg_node(int n,
                                         const float* __restrict__ xl,
                                         const float* __restrict__ as_a,
                                         const float* __restrict__ ad_a,
                                         const float* __restrict__ aself,
                                         const int* __restrict__ off,
                                         const int* __restrict__ deg,
                                         const int* __restrict__ csr_src,
                                         const float* __restrict__ csr_aed,
                                         const float* __restrict__ gbias,
                                         float* __restrict__ dst){
  const int lane = threadIdx.x & 63;
  const int o = off[n], d = deg[n];
  const float ad_n = ad_a[n];
  float a_self = as_a[n] + ad_n + aself[n];
  a_self = a_self > 0.f ? a_self : a_self*NEG;
  float m = -1e30f, s = 0.f;
  for (int i = lane; i < d; i += 64){
    int si = csr_src[o+i];
    float a = as_a[si] + ad_n + csr_aed[o+i];
    a = a > 0.f ? a : a*NEG;
    if (a > m){ s = s*__expf(m - a) + 1.f; m = a; }
    else s += __expf(a - m);
  }
  #pragma unroll
  for (int w=32; w>=1; w>>=1){
    float mo = __shfl_xor(m, w);
    float so = __shfl_xor(s, w);
    float M = fmaxf(m, mo);
    s = s*__expf(m - M) + so*__expf(mo - M);
    m = M;
  }
  { float M = fmaxf(m, a_self);
    s = s*__expf(m - M) + __expf(a_self - M);
    m = M; }
  const float inv = 1.f / s;
  float accx = 0.f, accy = 0.f;
  const float* xlane = xl + lane*2;
  for (int c = 0; c < d; c += 64){
    int i = c + lane;
    float w = 0.f; int si = 0;
    if (i < d){
      si = csr_src[o+i];
      float a = as_a[si] + ad_n + csr_aed[o+i];
      a = a > 0.f ? a : a*NEG;
      w = __expf(a - m)*inv;
    }
    const int cnt = (d - c) < 64 ? (d - c) : 64;
    int j = 0;
    for (; j + 4 <= cnt; j += 4){
      int   s0 = __shfl(si, j),   s1 = __shfl(si, j+1),
            s2 = __shfl(si, j+2), s3 = __shfl(si, j+3);
      float w0 = __shfl(w, j),    w1 = __shfl(w, j+1),
            w2 = __shfl(w, j+2),  w3 = __shfl(w, j+3);
      float2 v0 = *(const float2*)(xlane + (size_t)s0*HID);
      float2 v1 = *(const float2*)(xlane + (size_t)s1*HID);
      float2 v2 = *(const float2*)(xlane + (size_t)s2*HID);
      float2 v3 = *(const float2*)(xlane + (size_t)s3*HID);
      accx += w0*v0.x + w1*v1.x + w2*v2.x + w3*v3.x;
      accy += w0*v0.y + w1*v1.y + w2*v2.y + w3*v3.y;
    }
    for (; j < cnt; ++j){
      int   sj = __shfl(si, j);
      float wj = __shfl(w, j);
      float2 v = *(const float2*)(xlane + (size_t)sj*HID);
      accx += wj*v.x; accy += wj*v.y;
    }
  }
  { float w = __expf(a_self - m)*inv;
    const float2 v = *(const float2*)(xlane + (size_t)n*HID);
    accx += w*v.x; accy += w*v.y; }
  float2 ov;
  ov.x = accx + gbias[lane*2];
  ov.y = accy + gbias[lane*2+1];
  *(float2*)(dst + lane*2) = ov;
}

// full aggregation, XCD-swizzled
__global__ __launch_bounds__(256) void k_agg(const float* __restrict__ xl,
                                             const float* __restrict__ as_a,
                                             const float* __restrict__ ad_a,
                                             const float* __restrict__ aself,
                                             const int* __restrict__ off,
                                             const int* __restrict__ deg,
                                             const int* __restrict__ csr_src,
                                             const float* __restrict__ csr_aed,
                                             const float* __restrict__ gbias,
                                             float* __restrict__ nodes){
  const int nb = blockIdx.x;
  const int idx = (nb & 7)*1002 + (nb >> 3);
  const int n = idx*4 + (threadIdx.x >> 6);
  if (n >= NN) return;
  agg_node(n, xl, as_a, ad_a, aself, off, deg, csr_src, csr_aed, gbias,
           nodes + (size_t)n*HID);
}

// aggregation for rows 0..10 of each graph only (hop-2: only these feed hop-3)
__global__ __launch_bounds__(256) void k_agg_small(const float* __restrict__ xl,
                                                   const float* __restrict__ as_a,
                                                   const float* __restrict__ ad_a,
                                                   const float* __restrict__ aself,
                                                   const int* __restrict__ off,
                                                   const int* __restrict__ deg,
                                                   const int* __restrict__ csr_src,
                                                   const float* __restrict__ csr_aed,
                                                   const float* __restrict__ gbias,
                                                   float* __restrict__ nodes){
  const int idx = blockIdx.x*4 + (threadIdx.x >> 6);
  if (idx >= BGR*11) return;
  const int g = idx / 11, r = idx - g*11;
  const int n = g*NPG + r;
  agg_node(n, xl, as_a, ad_a, aself, off, deg, csr_src, csr_aed, gbias,
           nodes + (size_t)n*HID);
}

// hop-3: aggregate ctx nodes only, write straight to d_out (fuses k_out)
__global__ __launch_bounds__(256) void k_agg_ctx(const float* __restrict__ xl,
                                                 const float* __restrict__ as_a,
                                                 const float* __restrict__ ad_a,
                                                 const float* __restrict__ aself,
                                                 const int* __restrict__ off,
                                                 const int* __restrict__ deg,
                                                 const int* __restrict__ csr_src,
                                                 const float* __restrict__ csr_aed,
                                                 const float* __restrict__ gbias,
                                                 float* __restrict__ out){
  const int g = blockIdx.x*4 + (threadIdx.x >> 6);
  if (g >= BGR) return;
  agg_node(g*NPG, xl, as_a, ad_a, aself, off, deg, csr_src, csr_aed, gbias,
           out + (size_t)g*HID);
}

extern "C" void kernel_launch(void* const* d_in, const int* in_sizes, int n_in,
                              void* d_out, int out_size, void* d_ws, size_t ws_size,
                              hipStream_t stream){
  (void)n_in; (void)out_size; (void)ws_size;
  const float* lm       = (const float*)d_in[0];
  const float* node_emb = (const float*)d_in[1];
  const int*   eidx     = (const int*)d_in[2];
  const int*   etype    = (const int*)d_in[3];
  const float* W_lm     = (const float*)d_in[5];
  const float* b_lm     = (const float*)d_in[6];
  const float* W_bil    = (const float*)d_in[7];
  const float* b_bil    = (const float*)d_in[8];
  const float* etab     = (const float*)d_in[9];
  const float* W_gat    = (const float*)d_in[10];
  const float* att_src  = (const float*)d_in[11];
  const float* att_dst  = (const float*)d_in[12];
  const float* W_edge   = (const float*)d_in[13];
  const float* att_edge = (const float*)d_in[14];
  const float* gbias    = (const float*)d_in[15];
  const int E = in_sizes[3];
  const int* src = eidx;
  const int* dst = eidx + E;

  char* p = (char*)d_ws;
  auto take = [&](size_t nbytes){ void* r = (void*)p; p += (nbytes + 255) & ~(size_t)255; return r; };
  float* nodes   = (float*)take((size_t)NN*HID*4);
  float* xl      = (float*)take((size_t)NN*HID*4);
  float* tmp01   = (float*)take((size_t)2*TPART*4);
  float* tmp23   = xl;                                  // alias: dead before k_xl
  float* ctx_emb = (float*)take((size_t)BGR*HID*4);
  float* as_a    = (float*)take((size_t)NN*4);
  float* ad_a    = (float*)take((size_t)NN*4);
  float* aself   = (float*)take((size_t)NN*4);
  float* asum    = (float*)take((size_t)NN*4);
  int*   deg     = (int*)take((size_t)NN*4);
  int*   off     = (int*)take((size_t)NN*4);
  int*   cursor  = (int*)take((size_t)NN*4);
  int*   counter = (int*)take(256);
  float* te      = (float*)take(256);
  int*   csr_src = (int*)take((size_t)E*4);
  float* csr_aed = (float*)take((size_t)E*4);
  short* lmb_hi  = (short*)take((size_t)BGR*LMD*2);
  short* lmb_lo  = (short*)take((size_t)BGR*LMD*2);
  short* wtg_hi  = (short*)take((size_t)HID*HID*2);
  short* wtg_lo  = (short*)take((size_t)HID*HID*2);

  k_setup<<<575,256,0,stream>>>(W_edge, att_edge, etab, te, W_gat, wtg_hi, wtg_lo,
                                lm, lmb_hi, lmb_lo, W_lm, b_lm, ctx_emb, deg, asum, counter);
  k_count<<<(E+255)/256,256,0,stream>>>(dst, etype, te, deg, asum, E);
  k_offsets<<<(NN+255)/256,256,0,stream>>>(deg, asum, off, cursor, aself, counter);
  k_fill<<<(E+255)/256,256,0,stream>>>(src, dst, etype, te, cursor, csr_src, csr_aed, E);
  k_tmp<<<512,256,0,stream>>>(lmb_hi, lmb_lo, W_bil, tmp01, tmp23);
  k_apply<<<BGR*16,256,0,stream>>>(node_emb, ctx_emb, tmp01, tmp23, b_bil, nodes);
  // hop 1: full
  k_xl<<<NN/64,256,0,stream>>>(nodes, wtg_hi, wtg_lo, att_src, att_dst, xl, as_a, ad_a);
  k_agg<<<NN/4,256,0,stream>>>(xl, as_a, ad_a, aself, off, deg, csr_src, csr_aed, gbias, nodes);
  // hop 2: full xl, but only rows 0..10/graph feed hop 3
  k_xl<<<NN/64,256,0,stream>>>(nodes, wtg_hi, wtg_lo, att_src, att_dst, xl, as_a, ad_a);
  k_agg_small<<<(BGR*11+3)/4,256,0,stream>>>(xl, as_a, ad_a, aself, off, deg, csr_src, csr_aed, gbias, nodes);
  // hop 3: only ctx output needed; sources are rows 1..10 (+self row 0)
  k_xl_small<<<BGR,256,0,stream>>>(nodes, W_gat, att_src, att_dst, xl, as_a, ad_a);
  k_agg_ctx<<<BGR/4,256,0,stream>>>(xl, as_a, ad_a, aself, off, deg, csr_src, csr_aed, gbias, (float*)d_out);
}

// Round 8
// 344.756 us; speedup vs baseline: 1.4811x; 1.0892x over previous
//
#include <hip/hip_runtime.h>
#include <hip/hip_bf16.h>

#define HID 128
#define LMD 1024
#define BGR 64
#define NPG 501
#define NN (BGR*NPG)
#define NRELT 42
#define NEG 0.2f
#define TPART ((size_t)BGR*HID*HID)

typedef short bf16x8 __attribute__((ext_vector_type(8)));
typedef short bf16x4 __attribute__((ext_vector_type(4)));
typedef float f32x4  __attribute__((ext_vector_type(4)));

__device__ __forceinline__ short f2bf(float x){
  union { float f; unsigned u; } v; v.f = x;
  unsigned r = v.u + 0x7FFFu + ((v.u >> 16) & 1u);
  return (short)(r >> 16);
}
__device__ __forceinline__ float bf2f(short h){
  union { unsigned u; float f; } v; v.u = ((unsigned)(unsigned short)h) << 16;
  return v.f;
}
__device__ __forceinline__ void fsplit(float x, short& hi, short& lo){
  hi = f2bf(x);
  lo = f2bf(x - bf2f(hi));
}

// merged setup: te / W_gat^T->bf16 hi+lo / lm->bf16 hi+lo / zero / ctx_emb
__global__ void k_setup(const float* __restrict__ W_edge, const float* __restrict__ att_edge,
                        const float* __restrict__ etab, float* __restrict__ te,
                        const float* __restrict__ W_gat, short* __restrict__ wtg_hi,
                        short* __restrict__ wtg_lo,
                        const float* __restrict__ lm, short* __restrict__ lmb_hi,
                        short* __restrict__ lmb_lo,
                        const float* __restrict__ W_lm, const float* __restrict__ b_lm,
                        float* __restrict__ ctx_emb,
                        int* __restrict__ deg, float* __restrict__ asum,
                        int* __restrict__ counter){
  const int bid = blockIdx.x, t = threadIdx.x;
  if (bid == 0){
    __shared__ float we[HID];
    if (t < HID){
      float s = 0.f;
      for (int j=0;j<HID;++j) s += W_edge[t*HID+j]*att_edge[j];
      we[t] = s;
    }
    __syncthreads();
    if (t < NRELT){
      float s = 0.f;
      for (int i=0;i<HID;++i) s += etab[t*HID+i]*we[i];
      te[t] = s;
    }
  } else if (bid <= 128){
    int k = bid - 1;
    if (t < HID){
      short h, l; fsplit(W_gat[(size_t)k*HID + t], h, l);
      wtg_hi[t*HID + k] = h; wtg_lo[t*HID + k] = l;
    }
  } else if (bid <= 384){
    int i = (bid-129)*256 + t;          // 0..65535 = 64*1024
    short h, l; fsplit(lm[i], h, l);
    lmb_hi[i] = h; lmb_lo[i] = l;
  } else if (bid <= 510){
    int i = (bid-385)*256 + t;
    if (i < NN){ deg[i]=0; asum[i]=0.f; }
    if (i == 0) counter[0]=0;
  } else {
    int b = bid - 511;                   // 0..63
    if (t < HID){
      const float* lr_ = lm + (size_t)b*LMD;
      float s = b_lm[t];
      for (int l=0;l<LMD;++l) s += lr_[l]*W_lm[(size_t)l*HID + t];
      ctx_emb[b*HID + t] = s;
    }
  }
}

__global__ void k_count(const int* __restrict__ dst, const int* __restrict__ et,
                        const float* __restrict__ te, int* __restrict__ deg,
                        float* __restrict__ asum, int E){
  int e = blockIdx.x*256 + threadIdx.x;
  if (e >= E) return;
  int d = dst[e];
  atomicAdd(&deg[d], 1);
  atomicAdd(&asum[d], te[et[e]]);
}

__global__ void k_offsets(const int* __restrict__ deg, const float* __restrict__ asum,
                          int* __restrict__ off, int* __restrict__ cursor,
                          float* __restrict__ aself, int* __restrict__ counter){
  int i = blockIdx.x*256 + threadIdx.x;
  if (i >= NN) return;
  int d = deg[i];
  int o = atomicAdd(counter, d);
  off[i] = o; cursor[i] = o;
  aself[i] = asum[i] / (float)(d > 1 ? d : 1);
}

__global__ void k_fill(const int* __restrict__ src, const int* __restrict__ dst,
                       const int* __restrict__ et, const float* __restrict__ te,
                       int* __restrict__ cursor, int* __restrict__ csr_src,
                       float* __restrict__ csr_aed, int E){
  int e = blockIdx.x*256 + threadIdx.x;
  if (e >= E) return;
  int d = dst[e];
  int pos = atomicAdd(&cursor[d], 1);
  csr_src[pos] = src[e];
  csr_aed[pos] = te[et[e]];
}

// tmp[b,k,h] = sum_l lm[b,l]*W_bil[k,l,h] via split-bf16 MFMA, v3:
// v2 was grid-starved (512 blocks = 2/CU, 15% occupancy, nothing busy).
// v3 splits the h-dim: each block stages 64 h rows (LDS 18.4 KB), grid 1024
// = 4 blocks/CU = 16 waves/CU. Fragment-major LDS kept (one ds_read_b128
// per fragment). k=bid>>3, hh=(bid>>2)&1, lq=bid&3.
__global__ __launch_bounds__(256) void k_tmp(const short* __restrict__ lmb_hi,
                                             const short* __restrict__ lmb_lo,
                                             const float* __restrict__ W_bil,
                                             float* __restrict__ tmp01,
                                             float* __restrict__ tmp23){
  const int k  = blockIdx.x >> 3;
  const int hh = (blockIdx.x >> 2) & 1;
  const int lq = blockIdx.x & 3;
  const int lbase = lq*256;
  __shared__ short Bhi[64*72];   // Bhi[h_local][l'], stride 72 shorts
  __shared__ short Blo[64*72];
  const int tid = threadIdx.x;
  const int ln = tid & 63, wv = tid >> 6;
  const int lr = ln & 15, lk = ln >> 4;
  const int hl = tid & 63;       // local h row this thread stages
  const int qh = tid >> 6;       // 0..3 -> stages q = 2qh, 2qh+1
  f32x4 acc[4];
  #pragma unroll
  for (int i=0;i<4;++i) acc[i] = (f32x4){0.f,0.f,0.f,0.f};
  for (int c=0;c<4;++c){
    if (c) __syncthreads();
    const float* wp = W_bil + ((size_t)k*LMD + lbase + c*64)*HID + hh*64 + hl;
    #pragma unroll
    for (int p=0;p<2;++p){
      const int q = qh*2 + p;          // l'-group 0..7
      bf16x8 hi8, lo8;
      #pragma unroll
      for (int i=0;i<8;++i){
        short h_, l_; fsplit(wp[(size_t)(q*8+i)*HID], h_, l_);
        hi8[i]=h_; lo8[i]=l_;
      }
      *(bf16x8*)&Bhi[hl*72 + q*8] = hi8;
      *(bf16x8*)&Blo[hl*72 + q*8] = lo8;
    }
    __syncthreads();
    #pragma unroll
    for (int ks=0;ks<2;++ks){
      const size_t aoff = (size_t)(wv*16+lr)*LMD + lbase + c*64 + ks*32 + lk*8;
      bf16x8 ah = *(const bf16x8*)(lmb_hi + aoff);
      bf16x8 al = *(const bf16x8*)(lmb_lo + aoff);
      #pragma unroll
      for (int ct=0;ct<4;++ct){
        const int bo = (ct*16+lr)*72 + ks*32 + lk*8;
        bf16x8 bh = *(const bf16x8*)&Bhi[bo];
        bf16x8 bl = *(const bf16x8*)&Blo[bo];
        acc[ct] = __builtin_amdgcn_mfma_f32_16x16x32_bf16(ah, bh, acc[ct], 0, 0, 0);
        acc[ct] = __builtin_amdgcn_mfma_f32_16x16x32_bf16(ah, bl, acc[ct], 0, 0, 0);
        acc[ct] = __builtin_amdgcn_mfma_f32_16x16x32_bf16(al, bh, acc[ct], 0, 0, 0);
      }
    }
  }
  float* out = (lq < 2) ? (tmp01 + (size_t)lq*TPART) : (tmp23 + (size_t)(lq-2)*TPART);
  const int brow = wv*16 + lk*4;
  #pragma unroll
  for (int ct=0; ct<4; ++ct){
    int hg = hh*64 + ct*16 + lr;
    #pragma unroll
    for (int j=0;j<4;++j)
      out[ ((size_t)(brow + j)*HID + k)*HID + hg ] = acc[ct][j];
  }
}

// nodes[g*NPG+n, k] = sum_h (4 tmp partials)[g,k,h]*x[g,n,h] + b_bil[k]
__global__ __launch_bounds__(256) void k_apply(const float* __restrict__ node_emb,
                                               const float* __restrict__ ctx_emb,
                                               const float* __restrict__ tmp01,
                                               const float* __restrict__ tmp23,
                                               const float* __restrict__ b_bil,
                                               float* __restrict__ nodes){
  const int bid = blockIdx.x;
  const int g  = bid >> 4;
  const int rt = (bid >> 1) & 7;
  const int kt = bid & 1;
  const int n0 = rt*64, k0 = kt*64;
  __shared__ float As[32][65];
  __shared__ float Bs[32][65];
  const int tid = threadIdx.x, ty = tid>>4, tx = tid&15;
  float acc[4][4] = {};
  const int lr = tid >> 2, lc = (tid & 3) * 8;
  const float* xrow = nullptr;
  {
    int nl = n0 + lr;
    if (nl < NPG) xrow = (nl == 0) ? (ctx_emb + (size_t)g*HID)
                                   : (node_emb + ((size_t)(g*NPG + nl))*HID);
  }
  const float* pA = tmp01 + ((size_t)(g*HID + k0 + lr))*HID;
  const float* pB = pA + TPART;
  const float* pC = tmp23 + ((size_t)(g*HID + k0 + lr))*HID;
  const float* pD = pC + TPART;
  for (int h0c = 0; h0c < HID; h0c += 32){
    #pragma unroll
    for (int j=0;j<8;++j) As[lc+j][lr] = xrow ? xrow[h0c + lc + j] : 0.f;
    #pragma unroll
    for (int j=0;j<8;++j) Bs[lc+j][lr] = pA[h0c+lc+j] + pB[h0c+lc+j] + pC[h0c+lc+j] + pD[h0c+lc+j];
    __syncthreads();
    #pragma unroll
    for (int hc=0;hc<32;++hc){
      float a[4], b[4];
      #pragma unroll
      for (int i=0;i<4;++i) a[i] = As[hc][ty*4+i];
      #pragma unroll
      for (int j=0;j<4;++j) b[j] = Bs[hc][tx*4+j];
      #pragma unroll
      for (int i=0;i<4;++i)
        #pragma unroll
        for (int j=0;j<4;++j) acc[i][j] += a[i]*b[j];
    }
    __syncthreads();
  }
  float bb[4];
  #pragma unroll
  for (int j=0;j<4;++j) bb[j] = b_bil[k0 + tx*4 + j];
  #pragma unroll
  for (int i=0;i<4;++i){
    int nl = n0 + ty*4 + i;
    if (nl < NPG){
      float* o = nodes + ((size_t)(g*NPG + nl))*HID + k0 + tx*4;
      #pragma unroll
      for (int j=0;j<4;++j) o[j] = acc[i][j] + bb[j];
    }
  }
}

// xl = nodes @ W_gat via split-bf16 MFMA; as/ad fused epilogue. 64 rows/block.
#define LDB 140
__global__ __launch_bounds__(256) void k_xl(const float* __restrict__ nodes,
                                            const short* __restrict__ wtg_hi,
                                            const short* __restrict__ wtg_lo,
                                            const float* __restrict__ att_src,
                                            const float* __restrict__ att_dst,
                                            float* __restrict__ xl,
                                            float* __restrict__ as_a,
                                            float* __restrict__ ad_a){
  __shared__ short Bth[128*LDB];
  __shared__ short Btl[128*LDB];
  const int tid = threadIdx.x;
  {
    int n = tid >> 1, half = tid & 1;
    const bf16x4* sh = (const bf16x4*)(wtg_hi + n*HID + half*64);
    const bf16x4* sl = (const bf16x4*)(wtg_lo + n*HID + half*64);
    short* dh = &Bth[n*LDB + half*64];
    short* dl = &Btl[n*LDB + half*64];
    #pragma unroll
    for (int i=0;i<16;++i){ *(bf16x4*)(dh + i*4) = sh[i]; *(bf16x4*)(dl + i*4) = sl[i]; }
  }
  __syncthreads();
  const int ln = tid & 63, wv = tid >> 6;
  const int lr = ln & 15, lk = ln >> 4;
  const int row0 = blockIdx.x*64 + wv*16;
  bf16x8 ah[4], al[4];
  {
    int r = row0 + lr;
    if (r >= NN) r = NN-1;
    const float* ap = nodes + (size_t)r*HID + lk*8;
    #pragma unroll
    for (int ks=0;ks<4;++ks){
      float4 x0 = *(const float4*)(ap + ks*32);
      float4 x1 = *(const float4*)(ap + ks*32 + 4);
      bf16x8 fh, fl;
      short h, l;
      fsplit(x0.x,h,l); fh[0]=h; fl[0]=l;
      fsplit(x0.y,h,l); fh[1]=h; fl[1]=l;
      fsplit(x0.z,h,l); fh[2]=h; fl[2]=l;
      fsplit(x0.w,h,l); fh[3]=h; fl[3]=l;
      fsplit(x1.x,h,l); fh[4]=h; fl[4]=l;
      fsplit(x1.y,h,l); fh[5]=h; fl[5]=l;
      fsplit(x1.z,h,l); fh[6]=h; fl[6]=l;
      fsplit(x1.w,h,l); fh[7]=h; fl[7]=l;
      ah[ks]=fh; al[ks]=fl;
    }
  }
  f32x4 acc[8];
  #pragma unroll
  for (int ct=0;ct<8;++ct) acc[ct] = (f32x4){0.f,0.f,0.f,0.f};
  #pragma unroll
  for (int ct=0;ct<8;++ct){
    #pragma unroll
    for (int ks=0;ks<4;++ks){
      const int bo = (ct*16+lr)*LDB + ks*32 + lk*8;
      bf16x4 h0 = *(const bf16x4*)&Bth[bo];
      bf16x4 h1 = *(const bf16x4*)&Bth[bo+4];
      bf16x4 l0 = *(const bf16x4*)&Btl[bo];
      bf16x4 l1 = *(const bf16x4*)&Btl[bo+4];
      bf16x8 bh, bl;
      bh[0]=h0[0];bh[1]=h0[1];bh[2]=h0[2];bh[3]=h0[3];
      bh[4]=h1[0];bh[5]=h1[1];bh[6]=h1[2];bh[7]=h1[3];
      bl[0]=l0[0];bl[1]=l0[1];bl[2]=l0[2];bl[3]=l0[3];
      bl[4]=l1[0];bl[5]=l1[1];bl[6]=l1[2];bl[7]=l1[3];
      acc[ct] = __builtin_amdgcn_mfma_f32_16x16x32_bf16(ah[ks], bh, acc[ct], 0, 0, 0);
      acc[ct] = __builtin_amdgcn_mfma_f32_16x16x32_bf16(ah[ks], bl, acc[ct], 0, 0, 0);
      acc[ct] = __builtin_amdgcn_mfma_f32_16x16x32_bf16(al[ks], bh, acc[ct], 0, 0, 0);
    }
  }
  float asv[8], adv[8];
  #pragma unroll
  for (int ct=0;ct<8;++ct){ asv[ct]=att_src[ct*16+lr]; adv[ct]=att_dst[ct*16+lr]; }
  #pragma unroll
  for (int j=0;j<4;++j){
    int r = row0 + lk*4 + j;
    float ps=0.f, pd=0.f;
    #pragma unroll
    for (int ct=0;ct<8;++ct){
      float v = acc[ct][j];
      ps += v*asv[ct]; pd += v*adv[ct];
      if (r < NN) xl[(size_t)r*HID + ct*16 + lr] = v;
    }
    #pragma unroll
    for (int msk=8;msk>=1;msk>>=1){ ps += __shfl_xor(ps,msk); pd += __shfl_xor(pd,msk); }
    if (lr == 0 && r < NN){ as_a[r]=ps; ad_a[r]=pd; }
  }
}

// f32 xl for rows 0..10 of each graph only (hop 3 needs just these)
__global__ __launch_bounds__(256) void k_xl_small(const float* __restrict__ nodes,
                                                  const float* __restrict__ W_gat,
                                                  const float* __restrict__ att_src,
                                                  const float* __restrict__ att_dst,
                                                  float* __restrict__ xl,
                                                  float* __restrict__ as_a,
                                                  float* __restrict__ ad_a){
  const int g = blockIdx.x, t = threadIdx.x;
  __shared__ float sn[11][HID];
  __shared__ float sx[11][HID];
  for (int idx = t; idx < 11*HID; idx += 256)
    sn[idx>>7][idx&127] = nodes[((size_t)g*NPG + (idx>>7))*HID + (idx&127)];
  __syncthreads();
  for (int idx = t; idx < 11*HID; idx += 256){
    const int r = idx>>7, h = idx&127;
    float s = 0.f;
    #pragma unroll 8
    for (int l=0;l<HID;++l) s += sn[r][l]*W_gat[(size_t)l*HID + h];
    sx[r][h] = s;
    xl[((size_t)g*NPG + r)*HID + h] = s;
  }
  __syncthreads();
  const int ln = t & 63, wv = t >> 6;
  for (int r = wv; r < 11; r += 4){
    float v0 = sx[r][ln], v1 = sx[r][64+ln];
    float ps = v0*att_src[ln] + v1*att_src[64+ln];
    float pd = v0*att_dst[ln] + v1*att_dst[64+ln];
    #pragma unroll
    for (int msk=32;msk>=1;msk>>=1){ ps += __shfl_xor(ps,msk); pd += __shfl_xor(pd,msk); }
    if (ln == 0){ as_a[(size_t)g*NPG + r] = ps; ad_a[(size_t)g*NPG + r] = pd; }
  }
}

// per-node softmax-weighted aggregation core (one wave per node)
__device__ __forceinline__ void agg_node(int n,
                                         const float* __restrict__ xl,
                                         const float* __restrict__ as_a,
                                         const float* __restrict__ ad_a,
                                         const float* __restrict__ aself,
                                         const int* __restrict__ off,
                                         const int* __restrict__ deg,
                                         const int* __restrict__ csr_src,
                                         const float* __restrict__ csr_aed,
                                         const float* __restrict__ gbias,
                                         float* __restrict__ dst){
  const int lane = threadIdx.x & 63;
  const int o = off[n], d = deg[n];
  const float ad_n = ad_a[n];
  float a_self = as_a[n] + ad_n + aself[n];
  a_self = a_self > 0.f ? a_self : a_self*NEG;
  float m = -1e30f, s = 0.f;
  for (int i = lane; i < d; i += 64){
    int si = csr_src[o+i];
    float a = as_a[si] + ad_n + csr_aed[o+i];
    a = a > 0.f ? a : a*NEG;
    if (a > m){ s = s*__expf(m - a) + 1.f; m = a; }
    else s += __expf(a - m);
  }
  #pragma unroll
  for (int w=32; w>=1; w>>=1){
    float mo = __shfl_xor(m, w);
    float so = __shfl_xor(s, w);
    float M = fmaxf(m, mo);
    s = s*__expf(m - M) + so*__expf(mo - M);
    m = M;
  }
  { float M = fmaxf(m, a_self);
    s = s*__expf(m - M) + __expf(a_self - M);
    m = M; }
  const float inv = 1.f / s;
  float accx = 0.f, accy = 0.f;
  const float* xlane = xl + lane*2;
  for (int c = 0; c < d; c += 64){
    int i = c + lane;
    float w = 0.f; int si = 0;
    if (i < d){
      si = csr_src[o+i];
      float a = as_a[si] + ad_n + csr_aed[o+i];
      a = a > 0.f ? a : a*NEG;
      w = __expf(a - m)*inv;
    }
    const int cnt = (d - c) < 64 ? (d - c) : 64;
    int j = 0;
    for (; j + 4 <= cnt; j += 4){
      int   s0 = __shfl(si, j),   s1 = __shfl(si, j+1),
            s2 = __shfl(si, j+2), s3 = __shfl(si, j+3);
      float w0 = __shfl(w, j),    w1 = __shfl(w, j+1),
            w2 = __shfl(w, j+2),  w3 = __shfl(w, j+3);
      float2 v0 = *(const float2*)(xlane + (size_t)s0*HID);
      float2 v1 = *(const float2*)(xlane + (size_t)s1*HID);
      float2 v2 = *(const float2*)(xlane + (size_t)s2*HID);
      float2 v3 = *(const float2*)(xlane + (size_t)s3*HID);
      accx += w0*v0.x + w1*v1.x + w2*v2.x + w3*v3.x;
      accy += w0*v0.y + w1*v1.y + w2*v2.y + w3*v3.y;
    }
    for (; j < cnt; ++j){
      int   sj = __shfl(si, j);
      float wj = __shfl(w, j);
      float2 v = *(const float2*)(xlane + (size_t)sj*HID);
      accx += wj*v.x; accy += wj*v.y;
    }
  }
  { float w = __expf(a_self - m)*inv;
    const float2 v = *(const float2*)(xlane + (size_t)n*HID);
    accx += w*v.x; accy += w*v.y; }
  float2 ov;
  ov.x = accx + gbias[lane*2];
  ov.y = accy + gbias[lane*2+1];
  *(float2*)(dst + lane*2) = ov;
}

// full aggregation, XCD-swizzled
__global__ __launch_bounds__(256) void k_agg(const float* __restrict__ xl,
                                             const float* __restrict__ as_a,
                                             const float* __restrict__ ad_a,
                                             const float* __restrict__ aself,
                                             const int* __restrict__ off,
                                             const int* __restrict__ deg,
                                             const int* __restrict__ csr_src,
                                             const float* __restrict__ csr_aed,
                                             const float* __restrict__ gbias,
                                             float* __restrict__ nodes){
  const int nb = blockIdx.x;
  const int idx = (nb & 7)*1002 + (nb >> 3);
  const int n = idx*4 + (threadIdx.x >> 6);
  if (n >= NN) return;
  agg_node(n, xl, as_a, ad_a, aself, off, deg, csr_src, csr_aed, gbias,
           nodes + (size_t)n*HID);
}

// aggregation for rows 0..10 of each graph only (hop-2)
__global__ __launch_bounds__(256) void k_agg_small(const float* __restrict__ xl,
                                                   const float* __restrict__ as_a,
                                                   const float* __restrict__ ad_a,
                                                   const float* __restrict__ aself,
                                                   const int* __restrict__ off,
                                                   const int* __restrict__ deg,
                                                   const int* __restrict__ csr_src,
                                                   const float* __restrict__ csr_aed,
                                                   const float* __restrict__ gbias,
                                                   float* __restrict__ nodes){
  const int idx = blockIdx.x*4 + (threadIdx.x >> 6);
  if (idx >= BGR*11) return;
  const int g = idx / 11, r = idx - g*11;
  const int n = g*NPG + r;
  agg_node(n, xl, as_a, ad_a, aself, off, deg, csr_src, csr_aed, gbias,
           nodes + (size_t)n*HID);
}

// hop-3: aggregate ctx nodes only, write straight to d_out
__global__ __launch_bounds__(256) void k_agg_ctx(const float* __restrict__ xl,
                                                 const float* __restrict__ as_a,
                                                 const float* __restrict__ ad_a,
                                                 const float* __restrict__ aself,
                                                 const int* __restrict__ off,
                                                 const int* __restrict__ deg,
                                                 const int* __restrict__ csr_src,
                                                 const float* __restrict__ csr_aed,
                                                 const float* __restrict__ gbias,
                                                 float* __restrict__ out){
  const int g = blockIdx.x*4 + (threadIdx.x >> 6);
  if (g >= BGR) return;
  agg_node(g*NPG, xl, as_a, ad_a, aself, off, deg, csr_src, csr_aed, gbias,
           out + (size_t)g*HID);
}

extern "C" void kernel_launch(void* const* d_in, const int* in_sizes, int n_in,
                              void* d_out, int out_size, void* d_ws, size_t ws_size,
                              hipStream_t stream){
  (void)n_in; (void)out_size; (void)ws_size;
  const float* lm       = (const float*)d_in[0];
  const float* node_emb = (const float*)d_in[1];
  const int*   eidx     = (const int*)d_in[2];
  const int*   etype    = (const int*)d_in[3];
  const float* W_lm     = (const float*)d_in[5];
  const float* b_lm     = (const float*)d_in[6];
  const float* W_bil    = (const float*)d_in[7];
  const float* b_bil    = (const float*)d_in[8];
  const float* etab     = (const float*)d_in[9];
  const float* W_gat    = (const float*)d_in[10];
  const float* att_src  = (const float*)d_in[11];
  const float* att_dst  = (const float*)d_in[12];
  const float* W_edge   = (const float*)d_in[13];
  const float* att_edge = (const float*)d_in[14];
  const float* gbias    = (const float*)d_in[15];
  const int E = in_sizes[3];
  const int* src = eidx;
  const int* dst = eidx + E;

  char* p = (char*)d_ws;
  auto take = [&](size_t nbytes){ void* r = (void*)p; p += (nbytes + 255) & ~(size_t)255; return r; };
  float* nodes   = (float*)take((size_t)NN*HID*4);
  float* xl      = (float*)take((size_t)NN*HID*4);
  float* tmp01   = (float*)take((size_t)2*TPART*4);
  float* tmp23   = xl;                                  // alias: dead before k_xl
  float* ctx_emb = (float*)take((size_t)BGR*HID*4);
  float* as_a    = (float*)take((size_t)NN*4);
  float* ad_a    = (float*)take((size_t)NN*4);
  float* aself   = (float*)take((size_t)NN*4);
  float* asum    = (float*)take((size_t)NN*4);
  int*   deg     = (int*)take((size_t)NN*4);
  int*   off     = (int*)take((size_t)NN*4);
  int*   cursor  = (int*)take((size_t)NN*4);
  int*   counter = (int*)take(256);
  float* te      = (float*)take(256);
  int*   csr_src = (int*)take((size_t)E*4);
  float* csr_aed = (float*)take((size_t)E*4);
  short* lmb_hi  = (short*)take((size_t)BGR*LMD*2);
  short* lmb_lo  = (short*)take((size_t)BGR*LMD*2);
  short* wtg_hi  = (short*)take((size_t)HID*HID*2);
  short* wtg_lo  = (short*)take((size_t)HID*HID*2);

  k_setup<<<575,256,0,stream>>>(W_edge, att_edge, etab, te, W_gat, wtg_hi, wtg_lo,
                                lm, lmb_hi, lmb_lo, W_lm, b_lm, ctx_emb, deg, asum, counter);
  k_count<<<(E+255)/256,256,0,stream>>>(dst, etype, te, deg, asum, E);
  k_offsets<<<(NN+255)/256,256,0,stream>>>(deg, asum, off, cursor, aself, counter);
  k_fill<<<(E+255)/256,256,0,stream>>>(src, dst, etype, te, cursor, csr_src, csr_aed, E);
  k_tmp<<<1024,256,0,stream>>>(lmb_hi, lmb_lo, W_bil, tmp01, tmp23);
  k_apply<<<BGR*16,256,0,stream>>>(node_emb, ctx_emb, tmp01, tmp23, b_bil, nodes);
  // hop 1: full
  k_xl<<<NN/64,256,0,stream>>>(nodes, wtg_hi, wtg_lo, att_src, att_dst, xl, as_a, ad_a);
  k_agg<<<NN/4,256,0,stream>>>(xl, as_a, ad_a, aself, off, deg, csr_src, csr_aed, gbias, nodes);
  // hop 2: full xl, but only rows 0..10/graph feed hop 3
  k_xl<<<NN/64,256,0,stream>>>(nodes, wtg_hi, wtg_lo, att_src, att_dst, xl, as_a, ad_a);
  k_agg_small<<<(BGR*11+3)/4,256,0,stream>>>(xl, as_a, ad_a, aself, off, deg, csr_src, csr_aed, gbias, nodes);
  // hop 3: only ctx output needed
  k_xl_small<<<BGR,256,0,stream>>>(nodes, W_gat, att_src, att_dst, xl, as_a, ad_a);
  k_agg_ctx<<<BGR/4,256,0,stream>>>(xl, as_a, ad_a, aself, off, deg, csr_src, csr_aed, gbias, (float*)d_out);
}